// Round 7
// baseline (237.239 us; speedup 1.0000x reference)
//
#include <hip/hip_runtime.h>
#include <hip/hip_bf16.h>
#include <math.h>
#include <stdint.h>

#define B 4
#define S 2048
#define D 512
#define H 8
#define HD 64

typedef __attribute__((ext_vector_type(4))) int   int4v;
typedef __attribute__((ext_vector_type(8))) short short8;
typedef __attribute__((ext_vector_type(4))) short short4v;
typedef __attribute__((ext_vector_type(4))) float f32x4;

__device__ __forceinline__ unsigned short bfr(float x) {
    __bf16 h = (__bf16)x;
    union { __bf16 b; unsigned short s; } u; u.b = h; return u.s;
}
// single v_exp_f32 (library exp2f drags in fixup code -> VALU hog)
__device__ __forceinline__ float ex2(float x) {
#if __has_builtin(__builtin_amdgcn_exp2f)
    return __builtin_amdgcn_exp2f(x);
#else
    return exp2f(x);
#endif
}

// log2e / sqrt(512): folded into Qh at projection time
#define QSCALE 0.06377229601488305f
// fixed log2-domain softmax max (scores |z| <~ 1; exact for any M). With
// k-split this makes partial (acc, l) sums EXACTLY mergeable by addition.
#define MFIX 4.0f

// async global->LDS: 16 B per lane, dest = wave-uniform base + lane*16
typedef const __attribute__((address_space(1))) unsigned char g8_t;
typedef __attribute__((address_space(3))) unsigned char l8_t;
__device__ __forceinline__ void gl_lds16(const unsigned short* g, unsigned short* l) {
#if __has_builtin(__builtin_amdgcn_global_load_lds)
    __builtin_amdgcn_global_load_lds((g8_t*)g, (l8_t*)l, 16, 0, 0);
#else
    int lane = threadIdx.x & 63;
    ((int4v*)l)[lane] = *(const int4v*)g;
#endif
}

// ---------------------------------------------------------------------------
// Kernel 0: convert Wo, Wq, Wk, Wv to bf16 once.
// ---------------------------------------------------------------------------
__global__ __launch_bounds__(256) void wcvt_kernel(
    const float* __restrict__ Wo, const float* __restrict__ Wq,
    const float* __restrict__ Wk, const float* __restrict__ Wv,
    unsigned short* __restrict__ WoB, unsigned short* __restrict__ WqB,
    unsigned short* __restrict__ WkB, unsigned short* __restrict__ WvB)
{
    int bid = blockIdx.x;
    const float* src; unsigned short* dst; int base;
    if (bid < 256)      { src = Wo; dst = WoB; base = bid * 1024; }
    else if (bid < 260) { src = Wq; dst = WqB; base = (bid - 256) * 1024; }
    else if (bid < 264) { src = Wk; dst = WkB; base = (bid - 260) * 1024; }
    else                { src = Wv; dst = WvB; base = (bid - 264) * 1024; }
    int i = base + threadIdx.x * 4;
    float4 f = *(const float4*)(src + i);
    short4v s;
    s[0] = (short)bfr(f.x); s[1] = (short)bfr(f.y);
    s[2] = (short)bfr(f.z); s[3] = (short)bfr(f.w);
    *(short4v*)(dst + i) = s;
}

// ---------------------------------------------------------------------------
// Kernel 1: QKV projection, LDS-free. One wave = (s-tile of 16, head, x).
// x=0: Qh (scaled by QSCALE), x=1: Kh, both [B,H,S,HD] row-major.
// x=2: V^T computed DIRECTLY (A=Wv, B=x^T) -> VtG [B,H,HD,S], 32 B segments.
// ---------------------------------------------------------------------------
__global__ __launch_bounds__(256) void qkv_mfma_kernel(
    const float* __restrict__ q, const float* __restrict__ k,
    const float* __restrict__ v,
    const unsigned short* __restrict__ WqB, const float* __restrict__ bq,
    const unsigned short* __restrict__ WkB, const float* __restrict__ bk,
    const unsigned short* __restrict__ WvB, const float* __restrict__ bv,
    unsigned short* __restrict__ Qh, unsigned short* __restrict__ Kh,
    unsigned short* __restrict__ VtG)
{
    const int t = threadIdx.x;
    const int L = t & 63, w = t >> 6;
    const int c = L & 15, qd = L >> 4;
    const int task = blockIdx.x * 4 + w;     // 12288 tasks
    const int st = task & 127;
    const int h  = (task >> 7) & 7;
    const int b  = (task >> 10) & 3;
    const int x  = task >> 12;               // 0=q,1=k,2=v

    const unsigned short* WB = (x == 0) ? WqB : (x == 1) ? WkB : WvB;
    const float* bias_p      = (x == 0) ? bq  : (x == 1) ? bk  : bv;
    const float* X           = (x == 0) ? q   : (x == 1) ? k   : v;

    const float* xrow = X + ((size_t)(b * S + st * 16 + c)) * D + h * HD;
    short8 af[2];
    #pragma unroll
    for (int kc = 0; kc < 2; ++kc) {
        float4 f0 = *(const float4*)(xrow + kc * 32 + 8 * qd);
        float4 f1 = *(const float4*)(xrow + kc * 32 + 8 * qd + 4);
        short8 s8;
        s8[0] = (short)bfr(f0.x); s8[1] = (short)bfr(f0.y);
        s8[2] = (short)bfr(f0.z); s8[3] = (short)bfr(f0.w);
        s8[4] = (short)bfr(f1.x); s8[5] = (short)bfr(f1.y);
        s8[6] = (short)bfr(f1.z); s8[7] = (short)bfr(f1.w);
        af[kc] = s8;
    }

    if (x < 2) {
        f32x4 acc[4];
        #pragma unroll
        for (int nt = 0; nt < 4; ++nt) {
            float bv_ = bias_p[16 * nt + c];
            acc[nt] = (f32x4){bv_, bv_, bv_, bv_};
            short8 b0 = *(const short8*)(WB + (16 * nt + c) * HD + 8 * qd);
            short8 b1 = *(const short8*)(WB + (16 * nt + c) * HD + 32 + 8 * qd);
            acc[nt] = __builtin_amdgcn_mfma_f32_16x16x32_bf16(af[0], b0, acc[nt], 0, 0, 0);
            acc[nt] = __builtin_amdgcn_mfma_f32_16x16x32_bf16(af[1], b1, acc[nt], 0, 0, 0);
        }
        unsigned short* O = ((x == 0) ? Qh : Kh)
                          + ((size_t)(b * H + h) * S + st * 16) * HD;
        const float sc = (x == 0) ? QSCALE : 1.0f;
        #pragma unroll
        for (int nt = 0; nt < 4; ++nt)
            #pragma unroll
            for (int r = 0; r < 4; ++r)
                O[(4 * qd + r) * HD + 16 * nt + c] = bfr(acc[nt][r] * sc);
    } else {
        f32x4 acc[4];
        #pragma unroll
        for (int nt = 0; nt < 4; ++nt) {
            float4 bb4 = *(const float4*)(bias_p + 16 * nt + 4 * qd);
            acc[nt] = (f32x4){bb4.x, bb4.y, bb4.z, bb4.w};
            short8 a0 = *(const short8*)(WB + (16 * nt + c) * HD + 8 * qd);
            short8 a1 = *(const short8*)(WB + (16 * nt + c) * HD + 32 + 8 * qd);
            acc[nt] = __builtin_amdgcn_mfma_f32_16x16x32_bf16(a0, af[0], acc[nt], 0, 0, 0);
            acc[nt] = __builtin_amdgcn_mfma_f32_16x16x32_bf16(a1, af[1], acc[nt], 0, 0, 0);
        }
        unsigned short* O = VtG + (size_t)(b * H + h) * HD * S;
        #pragma unroll
        for (int nt = 0; nt < 4; ++nt)
            #pragma unroll
            for (int r = 0; r < 4; ++r)
                O[(size_t)(16 * nt + 4 * qd + r) * S + st * 16 + c] = bfr(acc[nt][r]);
    }
}

// ---------------------------------------------------------------------------
// Kernel 2: MFMA flash attention, fixed-max softmax, SPLIT-K (2 slices).
// V staging slot XOR-swizzled by 4*sp (writer) / 4*p (reader) — identical
// permutation both sides, kills the 4-way ds_write bank conflict.
// ---------------------------------------------------------------------------
__global__ __launch_bounds__(256, 4) void attn_kernel(
    const unsigned short* __restrict__ Qh, const unsigned short* __restrict__ Kh,
    const unsigned short* __restrict__ VtG, float* __restrict__ accP,
    float* __restrict__ lP)
{
    __shared__ __align__(16) unsigned short Ks[2][4096];   // 16 KB
    __shared__ __align__(16) unsigned short Vs[2][4096];   // 16 KB

    const int idx = blockIdx.x;
    const int bh = idx >> 5;
    const int rem = idx & 31;
    const int qt = rem >> 1;               // 0..15
    const int ks = rem & 1;                // k-slice
    const int b = bh >> 3, h = bh & 7;
    const int t = threadIdx.x;
    const int w = t >> 6, L = t & 63;
    const int c = L & 15, qd = L >> 4;

    const unsigned short* Kb = Kh + ((size_t)bh * S + ks * 1024) * HD;
    const unsigned short* Vb = VtG + (size_t)bh * HD * S + ks * 1024;

    short8 qf[2][2];
    #pragma unroll
    for (int qg = 0; qg < 2; ++qg)
        #pragma unroll
        for (int kc = 0; kc < 2; ++kc)
            qf[qg][kc] = *(const short8*)(Qh
                + ((size_t)bh * S + qt * 128 + w * 32 + qg * 16 + c) * HD
                + kc * 32 + 8 * qd);

    f32x4 acc[2][4];
    float lrun[2] = {0.f, 0.f};
    #pragma unroll
    for (int qg = 0; qg < 2; ++qg)
        #pragma unroll
        for (int dt = 0; dt < 4; ++dt) acc[qg][dt] = (f32x4){0.f, 0.f, 0.f, 0.f};

    // V staging indices
    const int sd = t >> 3, sj = t & 7;
    const int sp = sj >> 2, smt = (sj >> 1) & 1;
    const int sqa = (2 * sj) & 3, sqb = (2 * sj + 1) & 3;
    const int sxor = sp << 2;              // lane-slot XOR (bank fix)

    int4v vpre[2];
    #pragma unroll
    for (int i = 0; i < 2; ++i) {
        int bi = w + 4 * i;
        gl_lds16(Kb + (size_t)(16 * (bi >> 1) + c) * HD + (bi & 1) * 32 + qd * 8,
                 &Ks[0][bi * 512]);
        vpre[i] = *(const int4v*)(Vb + (size_t)(sd + 32 * i) * S + 8 * sj);
    }

    for (int it = 0; it < 16; ++it) {
        const int cur = it & 1, nxt = cur ^ 1;
        // ---- write V_it into Vs[cur] (fragment order, XOR-swizzled slot) ----
        #pragma unroll
        for (int i = 0; i < 2; ++i) {
            int d = sd + 32 * i;
            int dt = d >> 4, cc = d & 15;
            union { int4v v; short4v h[2]; } u; u.v = vpre[i];
            *(short4v*)&Vs[cur][((dt * 2 + sp) * 64 + ((sqa * 16 + cc) ^ sxor)) * 8 + smt * 4] = u.h[0];
            *(short4v*)&Vs[cur][((dt * 2 + sp) * 64 + ((sqb * 16 + cc) ^ sxor)) * 8 + smt * 4] = u.h[1];
        }
        __syncthreads();
        if (it + 1 < 16) {
            int n1 = (it + 1) * 64;
            #pragma unroll
            for (int i = 0; i < 2; ++i) {
                int bi = w + 4 * i;
                gl_lds16(Kb + (size_t)(n1 + 16 * (bi >> 1) + c) * HD + (bi & 1) * 32 + qd * 8,
                         &Ks[nxt][bi * 512]);
                vpre[i] = *(const int4v*)(Vb + (size_t)(sd + 32 * i) * S + n1 + 8 * sj);
            }
        }

        const unsigned short* KsC = Ks[cur];
        const unsigned short* VsC = Vs[cur];

        // ---- ST = K.Q^T per mt, exp2 immediately, pack P ----
        short4v pa[2][4];
        #pragma unroll
        for (int mt = 0; mt < 4; ++mt) {
            short8 a0 = *(const short8*)(KsC + (mt * 2 + 0) * 512 + L * 8);
            short8 a1 = *(const short8*)(KsC + (mt * 2 + 1) * 512 + L * 8);
            #pragma unroll
            for (int qg = 0; qg < 2; ++qg) {
                f32x4 stv = (f32x4){-MFIX, -MFIX, -MFIX, -MFIX};
                stv = __builtin_amdgcn_mfma_f32_16x16x32_bf16(a0, qf[qg][0], stv, 0, 0, 0);
                stv = __builtin_amdgcn_mfma_f32_16x16x32_bf16(a1, qf[qg][1], stv, 0, 0, 0);
                float p0 = ex2(stv[0]), p1 = ex2(stv[1]);
                float p2 = ex2(stv[2]), p3 = ex2(stv[3]);
                lrun[qg] += (p0 + p1) + (p2 + p3);
                short4v p_;
                p_[0] = (short)bfr(p0); p_[1] = (short)bfr(p1);
                p_[2] = (short)bfr(p2); p_[3] = (short)bfr(p3);
                pa[qg][mt] = p_;
            }
        }

        // ---- PV: XOR-permuted lane-sequential b128 V-frag reads ----
        #pragma unroll
        for (int dt = 0; dt < 4; ++dt)
            #pragma unroll
            for (int p = 0; p < 2; ++p) {
                union { short8 v8; short4v h[2]; } u;
                u.v8 = *(const short8*)(VsC + (dt * 2 + p) * 512 + (L ^ (p << 2)) * 8);
#if __has_builtin(__builtin_amdgcn_mfma_f32_16x16x16bf16_1k)
                #pragma unroll
                for (int qg = 0; qg < 2; ++qg) {
                    acc[qg][dt] = __builtin_amdgcn_mfma_f32_16x16x16bf16_1k(
                        pa[qg][2 * p + 0], u.h[0], acc[qg][dt], 0, 0, 0);
                    acc[qg][dt] = __builtin_amdgcn_mfma_f32_16x16x16bf16_1k(
                        pa[qg][2 * p + 1], u.h[1], acc[qg][dt], 0, 0, 0);
                }
#else
                #pragma unroll
                for (int qg = 0; qg < 2; ++qg) {
                    short8 pz0 = {pa[qg][2 * p + 0][0], pa[qg][2 * p + 0][1],
                                  pa[qg][2 * p + 0][2], pa[qg][2 * p + 0][3], 0, 0, 0, 0};
                    short8 pz1 = {pa[qg][2 * p + 1][0], pa[qg][2 * p + 1][1],
                                  pa[qg][2 * p + 1][2], pa[qg][2 * p + 1][3], 0, 0, 0, 0};
                    short8 v0 = {u.h[0][0], u.h[0][1], u.h[0][2], u.h[0][3], 0, 0, 0, 0};
                    short8 v1 = {u.h[1][0], u.h[1][1], u.h[1][2], u.h[1][3], 0, 0, 0, 0};
                    acc[qg][dt] = __builtin_amdgcn_mfma_f32_16x16x32_bf16(pz0, v0, acc[qg][dt], 0, 0, 0);
                    acc[qg][dt] = __builtin_amdgcn_mfma_f32_16x16x32_bf16(pz1, v1, acc[qg][dt], 0, 0, 0);
                }
#endif
            }
    }

    const int q0 = qt * 128 + w * 32;
    float* accPp = accP + (size_t)ks * ((size_t)B * S * D)
                 + ((size_t)b * S + q0) * D + h * HD;
    #pragma unroll
    for (int qg = 0; qg < 2; ++qg) {
        float lr = lrun[qg];
        lr += __shfl_xor(lr, 16);
        lr += __shfl_xor(lr, 32);
        if (qd == 0)
            lP[(size_t)ks * ((size_t)B * H * S) + (size_t)bh * S + q0 + qg * 16 + c] = lr;
        #pragma unroll
        for (int dt = 0; dt < 4; ++dt)
            #pragma unroll
            for (int r = 0; r < 4; ++r)
                accPp[(size_t)(qg * 16 + 4 * qd + r) * D + 16 * dt + c] = acc[qg][dt][r];
    }
}

// ---------------------------------------------------------------------------
// Kernel 3: split-K merge + output projection + LayerNorm + residual.
// RE-GRIDDED: 512 blocks x 512 thr (16 rows, 8 waves of 64 cols each)
// -> 4096 waves = 4 waves/SIMD (was 1: all merge latency exposed).
// ---------------------------------------------------------------------------
__global__ __launch_bounds__(512) void oproj_ln_kernel(
    const float* __restrict__ accP, const float* __restrict__ lP,
    const unsigned short* __restrict__ WoB,
    const float* __restrict__ bo, const float* __restrict__ gamma,
    const float* __restrict__ beta, const float* __restrict__ qin,
    float* __restrict__ out)
{
    __shared__ __align__(16) unsigned short As[16 * 520];  // 16.6 KB
    __shared__ float red[2][8][16];
    __shared__ float linv_s[16][8];

    const int t = threadIdx.x;             // 0..511
    const int r0 = blockIdx.x * 16;
    const int w = t >> 6, L = t & 63;
    const int c = L & 15, qd = L >> 4;
    const int n0 = w * 64;
    const size_t NEf = (size_t)B * S * D;
    const size_t BHS = (size_t)B * H * S;

    if (t < 128) {                         // 1/(l0+l1) per (row, head)
        int row = t >> 3, hh = t & 7;
        int bb = r0 >> 11;
        int ss = (r0 & (S - 1)) + row;
        float l0 = lP[(size_t)(bb * H + hh) * S + ss];
        float l1 = lP[BHS + (size_t)(bb * H + hh) * S + ss];
        linv_s[row][hh] = 1.f / (l0 + l1);
    }
    __syncthreads();

    // stage merged A (bf16): 16 rows x 512 cols
    #pragma unroll
    for (int i = 0; i < 4; ++i) {
        int flat = t + 512 * i;
        int row = flat >> 7, cg = flat & 127;
        int col = cg * 4;
        size_t gi = (size_t)(r0 + row) * D + col;
        float4 a0 = *(const float4*)(accP + gi);
        float4 a1 = *(const float4*)(accP + NEf + gi);
        float li = linv_s[row][col >> 6];
        short4v s;
        s[0] = (short)bfr((a0.x + a1.x) * li);
        s[1] = (short)bfr((a0.y + a1.y) * li);
        s[2] = (short)bfr((a0.z + a1.z) * li);
        s[3] = (short)bfr((a0.w + a1.w) * li);
        *(short4v*)&As[row * 520 + col] = s;
    }
    __syncthreads();

    f32x4 acc[4];
    #pragma unroll
    for (int nt = 0; nt < 4; ++nt) {
        float bv_ = bo[n0 + 16 * nt + c];
        acc[nt] = (f32x4){bv_, bv_, bv_, bv_};
    }

    for (int kc = 0; kc < 16; ++kc) {
        short8 a0 = *(const short8*)&As[c * 520 + kc * 32 + 8 * qd];
        #pragma unroll
        for (int nt = 0; nt < 4; ++nt) {
            short8 bf = *(const short8*)(WoB + (size_t)(n0 + 16 * nt + c) * D
                                         + kc * 32 + 8 * qd);
            acc[nt] = __builtin_amdgcn_mfma_f32_16x16x32_bf16(a0, bf, acc[nt], 0, 0, 0);
        }
    }

    // LN stats: in-lane over 4 nt, shuffle over 16 c-lanes, LDS across 8 waves
    float sm[4], sq[4];
    #pragma unroll
    for (int r = 0; r < 4; ++r) { sm[r] = 0.f; sq[r] = 0.f; }
    #pragma unroll
    for (int nt = 0; nt < 4; ++nt)
        #pragma unroll
        for (int r = 0; r < 4; ++r) {
            float x_ = acc[nt][r];
            sm[r] += x_; sq[r] += x_ * x_;
        }
    #pragma unroll
    for (int mask = 1; mask <= 8; mask <<= 1)
        #pragma unroll
        for (int r = 0; r < 4; ++r) {
            sm[r] += __shfl_xor(sm[r], mask);
            sq[r] += __shfl_xor(sq[r], mask);
        }
    if (c == 0) {
        #pragma unroll
        for (int r = 0; r < 4; ++r) {
            red[0][w][4 * qd + r] = sm[r];
            red[1][w][4 * qd + r] = sq[r];
        }
    }
    __syncthreads();

    float mu[4], rs[4];
    #pragma unroll
    for (int r = 0; r < 4; ++r) {
        int m_ = 4 * qd + r;
        float s_ = 0.f, q_ = 0.f;
        #pragma unroll
        for (int w_ = 0; w_ < 8; ++w_) { s_ += red[0][w_][m_]; q_ += red[1][w_][m_]; }
        float mu_ = s_ * (1.f / D);
        float var = q_ * (1.f / D) - mu_ * mu_;    // population var (jnp.var)
        mu[r] = mu_;
        rs[r] = rsqrtf(var + 1e-5f);
    }

    #pragma unroll
    for (int nt = 0; nt < 4; ++nt) {
        int n = n0 + 16 * nt + c;
        float g = gamma[n], be = beta[n];
        #pragma unroll
        for (int r = 0; r < 4; ++r) {
            size_t gi = (size_t)(r0 + 4 * qd + r) * D + n;
            out[gi] = qin[gi] + (acc[nt][r] - mu[r]) * rs[r] * g + be;
        }
    }
}

// ---------------------------------------------------------------------------
extern "C" void kernel_launch(void* const* d_in, const int* in_sizes, int n_in,
                              void* d_out, int out_size, void* d_ws, size_t ws_size,
                              hipStream_t stream) {
    const float* q     = (const float*)d_in[0];
    const float* k     = (const float*)d_in[1];
    const float* v     = (const float*)d_in[2];
    const float* Wq    = (const float*)d_in[3];
    const float* bq    = (const float*)d_in[4];
    const float* Wk    = (const float*)d_in[5];
    const float* bk    = (const float*)d_in[6];
    const float* Wv    = (const float*)d_in[7];
    const float* bv    = (const float*)d_in[8];
    const float* Wo    = (const float*)d_in[9];
    const float* bo    = (const float*)d_in[10];
    const float* gamma = (const float*)d_in[11];
    const float* beta  = (const float*)d_in[12];
    float* out = (float*)d_out;

    const size_t NE = (size_t)B * S * D;          // 4,194,304
    unsigned short* wsu = (unsigned short*)d_ws;
    unsigned short* Qh  = wsu;                    // bf16 [B,H,S,HD]   8 MB
    unsigned short* Kh  = wsu + NE;               // bf16 [B,H,S,HD]   8 MB
    unsigned short* VtG = wsu + 2 * NE;           // bf16 [B,H,HD,S]   8 MB
    unsigned short* WoB = wsu + 3 * NE;           // bf16 [D,D]      0.5 MB
    unsigned short* WqB = WoB + (size_t)D * D;
    unsigned short* WkB = WqB + HD * HD;
    unsigned short* WvB = WkB + HD * HD;
    float* accP = (float*)(WvB + HD * HD);        // f32 [2][B,S,D]   32 MB
    float* lP   = accP + 2 * NE;                  // f32 [2][B,H,S]  0.5 MB

    hipLaunchKernelGGL(wcvt_kernel, dim3(268), dim3(256), 0, stream,
                       Wo, Wq, Wk, Wv, WoB, WqB, WkB, WvB);
    hipLaunchKernelGGL(qkv_mfma_kernel, dim3(3072), dim3(256), 0, stream,
                       q, k, v, WqB, bq, WkB, bk, WvB, bv, Qh, Kh, VtG);
    hipLaunchKernelGGL(attn_kernel, dim3(1024), dim3(256), 0, stream,
                       Qh, Kh, VtG, accP, lP);
    hipLaunchKernelGGL(oproj_ln_kernel, dim3(B * S / 16), dim3(512), 0, stream,
                       accP, lP, WoB, bo, gamma, beta, q, out);
}

// Round 8
// 217.622 us; speedup vs baseline: 1.0901x; 1.0901x over previous
//
#include <hip/hip_runtime.h>
#include <hip/hip_bf16.h>
#include <math.h>
#include <stdint.h>

#define B 4
#define S 2048
#define D 512
#define H 8
#define HD 64

typedef __attribute__((ext_vector_type(4))) int   int4v;
typedef __attribute__((ext_vector_type(8))) short short8;
typedef __attribute__((ext_vector_type(4))) short short4v;
typedef __attribute__((ext_vector_type(4))) float f32x4;

__device__ __forceinline__ unsigned short bfr(float x) {
    __bf16 h = (__bf16)x;
    union { __bf16 b; unsigned short s; } u; u.b = h; return u.s;
}
__device__ __forceinline__ float b2f(unsigned short s) {
    union { unsigned u; float f; } v; v.u = (unsigned)s << 16; return v.f;
}
// single v_exp_f32
__device__ __forceinline__ float ex2(float x) {
#if __has_builtin(__builtin_amdgcn_exp2f)
    return __builtin_amdgcn_exp2f(x);
#else
    return exp2f(x);
#endif
}
// load 8 consecutive fp32, pack to bf16 short8
__device__ __forceinline__ short8 cvt8(const float* p) {
    float4 f0 = *(const float4*)p;
    float4 f1 = *(const float4*)(p + 4);
    short8 s8;
    s8[0] = (short)bfr(f0.x); s8[1] = (short)bfr(f0.y);
    s8[2] = (short)bfr(f0.z); s8[3] = (short)bfr(f0.w);
    s8[4] = (short)bfr(f1.x); s8[5] = (short)bfr(f1.y);
    s8[6] = (short)bfr(f1.z); s8[7] = (short)bfr(f1.w);
    return s8;
}

// log2e / sqrt(512): folded into Qh at projection time
#define QSCALE 0.06377229601488305f
// fixed log2-domain softmax max (scores |z| <~ 1; exact for any M). With
// k-split this makes partial (acc, l) sums EXACTLY mergeable by addition.
#define MFIX 4.0f

// async global->LDS: 16 B per lane, dest = wave-uniform base + lane*16
typedef const __attribute__((address_space(1))) unsigned char g8_t;
typedef __attribute__((address_space(3))) unsigned char l8_t;
__device__ __forceinline__ void gl_lds16(const unsigned short* g, unsigned short* l) {
#if __has_builtin(__builtin_amdgcn_global_load_lds)
    __builtin_amdgcn_global_load_lds((g8_t*)g, (l8_t*)l, 16, 0, 0);
#else
    int lane = threadIdx.x & 63;
    ((int4v*)l)[lane] = *(const int4v*)g;
#endif
}

// ---------------------------------------------------------------------------
// Kernel 1: QKV projection (W converted inline from L2-hot fp32) + Wo->bf16
// conversion fused as tail blocks (blockIdx >= 3072).
// x=0: Qh (scaled by QSCALE), x=1: Kh, both [B,H,S,HD] row-major.
// x=2: V^T computed directly (A=Wv, B=x^T) -> VtG [B,H,HD,S].
// ---------------------------------------------------------------------------
__global__ __launch_bounds__(256) void qkv_mfma_kernel(
    const float* __restrict__ q, const float* __restrict__ k,
    const float* __restrict__ v,
    const float* __restrict__ Wq, const float* __restrict__ bq,
    const float* __restrict__ Wk, const float* __restrict__ bk,
    const float* __restrict__ Wv, const float* __restrict__ bv,
    const float* __restrict__ Wo, unsigned short* __restrict__ WoB,
    unsigned short* __restrict__ Qh, unsigned short* __restrict__ Kh,
    unsigned short* __restrict__ VtG)
{
    const int t = threadIdx.x;
    if (blockIdx.x >= 3072) {              // fused Wo conversion tail
        int i = (blockIdx.x - 3072) * 1024 + t * 4;
        float4 f = *(const float4*)(Wo + i);
        short4v s;
        s[0] = (short)bfr(f.x); s[1] = (short)bfr(f.y);
        s[2] = (short)bfr(f.z); s[3] = (short)bfr(f.w);
        *(short4v*)(WoB + i) = s;
        return;
    }

    const int L = t & 63, w = t >> 6;
    const int c = L & 15, qd = L >> 4;
    const int task = blockIdx.x * 4 + w;     // 12288 tasks
    const int st = task & 127;
    const int h  = (task >> 7) & 7;
    const int b  = (task >> 10) & 3;
    const int x  = task >> 12;               // 0=q,1=k,2=v

    const float* Wf     = (x == 0) ? Wq : (x == 1) ? Wk : Wv;
    const float* bias_p = (x == 0) ? bq : (x == 1) ? bk : bv;
    const float* X      = (x == 0) ? q  : (x == 1) ? k  : v;

    const float* xrow = X + ((size_t)(b * S + st * 16 + c)) * D + h * HD;
    short8 af[2];
    #pragma unroll
    for (int kc = 0; kc < 2; ++kc) af[kc] = cvt8(xrow + kc * 32 + 8 * qd);

    if (x < 2) {
        f32x4 acc[4];
        #pragma unroll
        for (int nt = 0; nt < 4; ++nt) {
            float bv_ = bias_p[16 * nt + c];
            acc[nt] = (f32x4){bv_, bv_, bv_, bv_};
            short8 b0 = cvt8(Wf + (16 * nt + c) * HD + 8 * qd);
            short8 b1 = cvt8(Wf + (16 * nt + c) * HD + 32 + 8 * qd);
            acc[nt] = __builtin_amdgcn_mfma_f32_16x16x32_bf16(af[0], b0, acc[nt], 0, 0, 0);
            acc[nt] = __builtin_amdgcn_mfma_f32_16x16x32_bf16(af[1], b1, acc[nt], 0, 0, 0);
        }
        unsigned short* O = ((x == 0) ? Qh : Kh)
                          + ((size_t)(b * H + h) * S + st * 16) * HD;
        const float sc = (x == 0) ? QSCALE : 1.0f;
        #pragma unroll
        for (int nt = 0; nt < 4; ++nt)
            #pragma unroll
            for (int r = 0; r < 4; ++r)
                O[(4 * qd + r) * HD + 16 * nt + c] = bfr(acc[nt][r] * sc);
    } else {
        f32x4 acc[4];
        #pragma unroll
        for (int nt = 0; nt < 4; ++nt) {
            float4 bb4 = *(const float4*)(bias_p + 16 * nt + 4 * qd);
            acc[nt] = (f32x4){bb4.x, bb4.y, bb4.z, bb4.w};
            short8 a0 = cvt8(Wf + (16 * nt + c) * HD + 8 * qd);
            short8 a1 = cvt8(Wf + (16 * nt + c) * HD + 32 + 8 * qd);
            acc[nt] = __builtin_amdgcn_mfma_f32_16x16x32_bf16(a0, af[0], acc[nt], 0, 0, 0);
            acc[nt] = __builtin_amdgcn_mfma_f32_16x16x32_bf16(a1, af[1], acc[nt], 0, 0, 0);
        }
        unsigned short* O = VtG + (size_t)(b * H + h) * HD * S;
        #pragma unroll
        for (int nt = 0; nt < 4; ++nt)
            #pragma unroll
            for (int r = 0; r < 4; ++r)
                O[(size_t)(16 * nt + 4 * qd + r) * S + st * 16 + c] = bfr(acc[nt][r]);
    }
}

// ---------------------------------------------------------------------------
// Kernel 2: MFMA flash attention, fixed-max softmax, SPLIT-K (2 slices).
// r6 staging (no XOR), builtin exp, bf16 partials, XCD-swizzled grid:
// bh = idx & 31 -> all 32 blocks of one (b,h) land on XCD bh&7 (K/V/Q
// fetched once per XCD, ~3 MB resident in its 4 MB L2).
// ---------------------------------------------------------------------------
__global__ __launch_bounds__(256, 4) void attn_kernel(
    const unsigned short* __restrict__ Qh, const unsigned short* __restrict__ Kh,
    const unsigned short* __restrict__ VtG, unsigned short* __restrict__ accPb,
    float* __restrict__ lP)
{
    __shared__ __align__(16) unsigned short Ks[2][4096];   // 16 KB
    __shared__ __align__(16) unsigned short Vs[2][4096];   // 16 KB

    const int idx = blockIdx.x;
    const int bh = idx & 31;               // XCD-locality swizzle
    const int rem = idx >> 5;
    const int qt = rem >> 1;               // 0..15
    const int ks = rem & 1;                // k-slice
    const int b = bh >> 3, h = bh & 7;
    const int t = threadIdx.x;
    const int w = t >> 6, L = t & 63;
    const int c = L & 15, qd = L >> 4;

    const unsigned short* Kb = Kh + ((size_t)bh * S + ks * 1024) * HD;
    const unsigned short* Vb = VtG + (size_t)bh * HD * S + ks * 1024;

    short8 qf[2][2];
    #pragma unroll
    for (int qg = 0; qg < 2; ++qg)
        #pragma unroll
        for (int kc = 0; kc < 2; ++kc)
            qf[qg][kc] = *(const short8*)(Qh
                + ((size_t)bh * S + qt * 128 + w * 32 + qg * 16 + c) * HD
                + kc * 32 + 8 * qd);

    f32x4 acc[2][4];
    float lrun[2] = {0.f, 0.f};
    #pragma unroll
    for (int qg = 0; qg < 2; ++qg)
        #pragma unroll
        for (int dt = 0; dt < 4; ++dt) acc[qg][dt] = (f32x4){0.f, 0.f, 0.f, 0.f};

    // V staging indices (r6 scheme)
    const int sd = t >> 3, sj = t & 7;
    const int sp = sj >> 2, smt = (sj >> 1) & 1;
    const int sqa = (2 * sj) & 3, sqb = (2 * sj + 1) & 3;

    int4v vpre[2];
    #pragma unroll
    for (int i = 0; i < 2; ++i) {
        int bi = w + 4 * i;
        gl_lds16(Kb + (size_t)(16 * (bi >> 1) + c) * HD + (bi & 1) * 32 + qd * 8,
                 &Ks[0][bi * 512]);
        vpre[i] = *(const int4v*)(Vb + (size_t)(sd + 32 * i) * S + 8 * sj);
    }

    for (int it = 0; it < 16; ++it) {
        const int cur = it & 1, nxt = cur ^ 1;
        #pragma unroll
        for (int i = 0; i < 2; ++i) {
            int d = sd + 32 * i;
            int dt = d >> 4, cc = d & 15;
            union { int4v v; short4v h[2]; } u; u.v = vpre[i];
            *(short4v*)&Vs[cur][((dt * 2 + sp) * 64 + sqa * 16 + cc) * 8 + smt * 4] = u.h[0];
            *(short4v*)&Vs[cur][((dt * 2 + sp) * 64 + sqb * 16 + cc) * 8 + smt * 4] = u.h[1];
        }
        __syncthreads();
        if (it + 1 < 16) {
            int n1 = (it + 1) * 64;
            #pragma unroll
            for (int i = 0; i < 2; ++i) {
                int bi = w + 4 * i;
                gl_lds16(Kb + (size_t)(n1 + 16 * (bi >> 1) + c) * HD + (bi & 1) * 32 + qd * 8,
                         &Ks[nxt][bi * 512]);
                vpre[i] = *(const int4v*)(Vb + (size_t)(sd + 32 * i) * S + n1 + 8 * sj);
            }
        }

        const unsigned short* KsC = Ks[cur];
        const unsigned short* VsC = Vs[cur];

        short4v pa[2][4];
        #pragma unroll
        for (int mt = 0; mt < 4; ++mt) {
            short8 a0 = *(const short8*)(KsC + (mt * 2 + 0) * 512 + L * 8);
            short8 a1 = *(const short8*)(KsC + (mt * 2 + 1) * 512 + L * 8);
            #pragma unroll
            for (int qg = 0; qg < 2; ++qg) {
                f32x4 stv = (f32x4){-MFIX, -MFIX, -MFIX, -MFIX};
                stv = __builtin_amdgcn_mfma_f32_16x16x32_bf16(a0, qf[qg][0], stv, 0, 0, 0);
                stv = __builtin_amdgcn_mfma_f32_16x16x32_bf16(a1, qf[qg][1], stv, 0, 0, 0);
                float p0 = ex2(stv[0]), p1 = ex2(stv[1]);
                float p2 = ex2(stv[2]), p3 = ex2(stv[3]);
                lrun[qg] += (p0 + p1) + (p2 + p3);
                short4v p_;
                p_[0] = (short)bfr(p0); p_[1] = (short)bfr(p1);
                p_[2] = (short)bfr(p2); p_[3] = (short)bfr(p3);
                pa[qg][mt] = p_;
            }
        }

        #pragma unroll
        for (int dt = 0; dt < 4; ++dt)
            #pragma unroll
            for (int p = 0; p < 2; ++p) {
                union { short8 v8; short4v h[2]; } u;
                u.v8 = *(const short8*)(VsC + (dt * 2 + p) * 512 + L * 8);
#if __has_builtin(__builtin_amdgcn_mfma_f32_16x16x16bf16_1k)
                #pragma unroll
                for (int qg = 0; qg < 2; ++qg) {
                    acc[qg][dt] = __builtin_amdgcn_mfma_f32_16x16x16bf16_1k(
                        pa[qg][2 * p + 0], u.h[0], acc[qg][dt], 0, 0, 0);
                    acc[qg][dt] = __builtin_amdgcn_mfma_f32_16x16x16bf16_1k(
                        pa[qg][2 * p + 1], u.h[1], acc[qg][dt], 0, 0, 0);
                }
#else
                #pragma unroll
                for (int qg = 0; qg < 2; ++qg) {
                    short8 pz0 = {pa[qg][2 * p + 0][0], pa[qg][2 * p + 0][1],
                                  pa[qg][2 * p + 0][2], pa[qg][2 * p + 0][3], 0, 0, 0, 0};
                    short8 pz1 = {pa[qg][2 * p + 1][0], pa[qg][2 * p + 1][1],
                                  pa[qg][2 * p + 1][2], pa[qg][2 * p + 1][3], 0, 0, 0, 0};
                    short8 v0 = {u.h[0][0], u.h[0][1], u.h[0][2], u.h[0][3], 0, 0, 0, 0};
                    short8 v1 = {u.h[1][0], u.h[1][1], u.h[1][2], u.h[1][3], 0, 0, 0, 0};
                    acc[qg][dt] = __builtin_amdgcn_mfma_f32_16x16x32_bf16(pz0, v0, acc[qg][dt], 0, 0, 0);
                    acc[qg][dt] = __builtin_amdgcn_mfma_f32_16x16x32_bf16(pz1, v1, acc[qg][dt], 0, 0, 0);
                }
#endif
            }
    }

    // ---- epilogue: bf16 partial acc + f32 partial l ----
    const int q0 = qt * 128 + w * 32;
    unsigned short* accPp = accPb + (size_t)ks * ((size_t)B * S * D)
                          + ((size_t)b * S + q0) * D + h * HD;
    #pragma unroll
    for (int qg = 0; qg < 2; ++qg) {
        float lr = lrun[qg];
        lr += __shfl_xor(lr, 16);
        lr += __shfl_xor(lr, 32);
        if (qd == 0)
            lP[(size_t)ks * ((size_t)B * H * S) + (size_t)bh * S + q0 + qg * 16 + c] = lr;
        #pragma unroll
        for (int dt = 0; dt < 4; ++dt)
            #pragma unroll
            for (int r = 0; r < 4; ++r)
                accPp[(size_t)(qg * 16 + 4 * qd + r) * D + 16 * dt + c]
                    = bfr(acc[qg][dt][r]);
    }
}

// ---------------------------------------------------------------------------
// Kernel 3: split-K merge (bf16 partials) + output projection + LN + residual.
// 512 blocks x 512 thr (16 rows; 8 waves of 64 cols) -> 4 waves/SIMD.
// ---------------------------------------------------------------------------
__global__ __launch_bounds__(512) void oproj_ln_kernel(
    const unsigned short* __restrict__ accPb, const float* __restrict__ lP,
    const unsigned short* __restrict__ WoB,
    const float* __restrict__ bo, const float* __restrict__ gamma,
    const float* __restrict__ beta, const float* __restrict__ qin,
    float* __restrict__ out)
{
    __shared__ __align__(16) unsigned short As[16 * 520];  // 16.6 KB
    __shared__ float red[2][8][16];
    __shared__ float linv_s[16][8];

    const int t = threadIdx.x;             // 0..511
    const int r0 = blockIdx.x * 16;
    const int w = t >> 6, L = t & 63;
    const int c = L & 15, qd = L >> 4;
    const int n0 = w * 64;
    const size_t NEh = (size_t)B * S * D;
    const size_t BHS = (size_t)B * H * S;

    if (t < 128) {                         // 1/(l0+l1) per (row, head)
        int row = t >> 3, hh = t & 7;
        int bb = r0 >> 11;
        int ss = (r0 & (S - 1)) + row;
        float l0 = lP[(size_t)(bb * H + hh) * S + ss];
        float l1 = lP[BHS + (size_t)(bb * H + hh) * S + ss];
        linv_s[row][hh] = 1.f / (l0 + l1);
    }
    __syncthreads();

    // stage merged A (bf16): 16 rows x 512 cols
    #pragma unroll
    for (int i = 0; i < 4; ++i) {
        int flat = t + 512 * i;
        int row = flat >> 7, cg = flat & 127;
        int col = cg * 4;
        size_t gi = (size_t)(r0 + row) * D + col;
        short4v a0 = *(const short4v*)(accPb + gi);
        short4v a1 = *(const short4v*)(accPb + NEh + gi);
        float li = linv_s[row][col >> 6];
        short4v s;
        #pragma unroll
        for (int j = 0; j < 4; ++j)
            s[j] = (short)bfr((b2f((unsigned short)a0[j])
                             + b2f((unsigned short)a1[j])) * li);
        *(short4v*)&As[row * 520 + col] = s;
    }
    __syncthreads();

    f32x4 acc[4];
    #pragma unroll
    for (int nt = 0; nt < 4; ++nt) {
        float bv_ = bo[n0 + 16 * nt + c];
        acc[nt] = (f32x4){bv_, bv_, bv_, bv_};
    }

    for (int kc = 0; kc < 16; ++kc) {
        short8 a0 = *(const short8*)&As[c * 520 + kc * 32 + 8 * qd];
        #pragma unroll
        for (int nt = 0; nt < 4; ++nt) {
            short8 bf = *(const short8*)(WoB + (size_t)(n0 + 16 * nt + c) * D
                                         + kc * 32 + 8 * qd);
            acc[nt] = __builtin_amdgcn_mfma_f32_16x16x32_bf16(a0, bf, acc[nt], 0, 0, 0);
        }
    }

    float sm[4], sq[4];
    #pragma unroll
    for (int r = 0; r < 4; ++r) { sm[r] = 0.f; sq[r] = 0.f; }
    #pragma unroll
    for (int nt = 0; nt < 4; ++nt)
        #pragma unroll
        for (int r = 0; r < 4; ++r) {
            float x_ = acc[nt][r];
            sm[r] += x_; sq[r] += x_ * x_;
        }
    #pragma unroll
    for (int mask = 1; mask <= 8; mask <<= 1)
        #pragma unroll
        for (int r = 0; r < 4; ++r) {
            sm[r] += __shfl_xor(sm[r], mask);
            sq[r] += __shfl_xor(sq[r], mask);
        }
    if (c == 0) {
        #pragma unroll
        for (int r = 0; r < 4; ++r) {
            red[0][w][4 * qd + r] = sm[r];
            red[1][w][4 * qd + r] = sq[r];
        }
    }
    __syncthreads();

    float mu[4], rs[4];
    #pragma unroll
    for (int r = 0; r < 4; ++r) {
        int m_ = 4 * qd + r;
        float s_ = 0.f, q_ = 0.f;
        #pragma unroll
        for (int w_ = 0; w_ < 8; ++w_) { s_ += red[0][w_][m_]; q_ += red[1][w_][m_]; }
        float mu_ = s_ * (1.f / D);
        float var = q_ * (1.f / D) - mu_ * mu_;    // population var (jnp.var)
        mu[r] = mu_;
        rs[r] = rsqrtf(var + 1e-5f);
    }

    #pragma unroll
    for (int nt = 0; nt < 4; ++nt) {
        int n = n0 + 16 * nt + c;
        float g = gamma[n], be = beta[n];
        #pragma unroll
        for (int r = 0; r < 4; ++r) {
            size_t gi = (size_t)(r0 + 4 * qd + r) * D + n;
            out[gi] = qin[gi] + (acc[nt][r] - mu[r]) * rs[r] * g + be;
        }
    }
}

// ---------------------------------------------------------------------------
extern "C" void kernel_launch(void* const* d_in, const int* in_sizes, int n_in,
                              void* d_out, int out_size, void* d_ws, size_t ws_size,
                              hipStream_t stream) {
    const float* q     = (const float*)d_in[0];
    const float* k     = (const float*)d_in[1];
    const float* v     = (const float*)d_in[2];
    const float* Wq    = (const float*)d_in[3];
    const float* bq    = (const float*)d_in[4];
    const float* Wk    = (const float*)d_in[5];
    const float* bk    = (const float*)d_in[6];
    const float* Wv    = (const float*)d_in[7];
    const float* bv    = (const float*)d_in[8];
    const float* Wo    = (const float*)d_in[9];
    const float* bo    = (const float*)d_in[10];
    const float* gamma = (const float*)d_in[11];
    const float* beta  = (const float*)d_in[12];
    float* out = (float*)d_out;

    const size_t NE = (size_t)B * S * D;          // 4,194,304
    unsigned short* wsu = (unsigned short*)d_ws;
    unsigned short* Qh    = wsu;                  // bf16 [B,H,S,HD]   8 MB
    unsigned short* Kh    = wsu + NE;             // bf16 [B,H,S,HD]   8 MB
    unsigned short* VtG   = wsu + 2 * NE;         // bf16 [B,H,HD,S]   8 MB
    unsigned short* WoB   = wsu + 3 * NE;         // bf16 [D,D]      0.5 MB
    unsigned short* accPb = WoB + (size_t)D * D;  // bf16 [2][B,S,D]  16 MB
    float* lP = (float*)(accPb + 2 * NE);         // f32 [2][B,H,S]  0.5 MB

    hipLaunchKernelGGL(qkv_mfma_kernel, dim3(3072 + 256), dim3(256), 0, stream,
                       q, k, v, Wq, bq, Wk, bk, Wv, bv, Wo, WoB, Qh, Kh, VtG);
    hipLaunchKernelGGL(attn_kernel, dim3(1024), dim3(256), 0, stream,
                       Qh, Kh, VtG, accPb, lP);
    hipLaunchKernelGGL(oproj_ln_kernel, dim3(B * S / 16), dim3(512), 0, stream,
                       accPb, lP, WoB, bo, gamma, beta, q, out);
}

// Round 9
// 192.481 us; speedup vs baseline: 1.2325x; 1.1306x over previous
//
#include <hip/hip_runtime.h>
#include <hip/hip_bf16.h>
#include <math.h>
#include <stdint.h>

#define B 4
#define S 2048
#define D 512
#define H 8
#define HD 64

typedef __attribute__((ext_vector_type(4))) int   int4v;
typedef __attribute__((ext_vector_type(8))) short short8;
typedef __attribute__((ext_vector_type(4))) short short4v;
typedef __attribute__((ext_vector_type(4))) float f32x4;

__device__ __forceinline__ unsigned short bfr(float x) {
    __bf16 h = (__bf16)x;
    union { __bf16 b; unsigned short s; } u; u.b = h; return u.s;
}
__device__ __forceinline__ float b2f(unsigned short s) {
    union { unsigned u; float f; } v; v.u = (unsigned)s << 16; return v.f;
}
__device__ __forceinline__ float ex2(float x) {
#if __has_builtin(__builtin_amdgcn_exp2f)
    return __builtin_amdgcn_exp2f(x);
#else
    return exp2f(x);
#endif
}
// load 8 consecutive fp32, pack to bf16 short8
__device__ __forceinline__ short8 cvt8(const float* p) {
    float4 f0 = *(const float4*)p;
    float4 f1 = *(const float4*)(p + 4);
    short8 s8;
    s8[0] = (short)bfr(f0.x); s8[1] = (short)bfr(f0.y);
    s8[2] = (short)bfr(f0.z); s8[3] = (short)bfr(f0.w);
    s8[4] = (short)bfr(f1.x); s8[5] = (short)bfr(f1.y);
    s8[6] = (short)bfr(f1.z); s8[7] = (short)bfr(f1.w);
    return s8;
}

// log2e / sqrt(512): folded into Qh at projection time
#define QSCALE 0.06377229601488305f
// fixed log2-domain softmax max (scores |z| <~ 1; exact for any M). With
// k-split this makes partial (acc, l) sums EXACTLY mergeable by addition.
#define MFIX 4.0f

// async global->LDS: 16 B per lane, dest = wave-uniform base + lane*16
typedef const __attribute__((address_space(1))) unsigned char g8_t;
typedef __attribute__((address_space(3))) unsigned char l8_t;
__device__ __forceinline__ void gl_lds16(const unsigned short* g, unsigned short* l) {
#if __has_builtin(__builtin_amdgcn_global_load_lds)
    __builtin_amdgcn_global_load_lds((g8_t*)g, (l8_t*)l, 16, 0, 0);
#else
    int lane = threadIdx.x & 63;
    ((int4v*)l)[lane] = *(const int4v*)g;
#endif
}

// ---------------------------------------------------------------------------
// Kernel 1: QKV projection. Block = (x, bh, 8 s-tiles); its ONE W matrix is
// cooperatively staged fp32->bf16 into LDS (coalesced), stride-72 rows so
// fragment ds_read_b128 is 2-way (free). Each wave reads W frags ONCE and
// processes 2 s-tiles (16 MFMAs). Wo->bf16 conversion fused as tail blocks.
// ---------------------------------------------------------------------------
__global__ __launch_bounds__(256) void qkv_mfma_kernel(
    const float* __restrict__ q, const float* __restrict__ k,
    const float* __restrict__ v,
    const float* __restrict__ Wq, const float* __restrict__ bq,
    const float* __restrict__ Wk, const float* __restrict__ bk,
    const float* __restrict__ Wv, const float* __restrict__ bv,
    const float* __restrict__ Wo, unsigned short* __restrict__ WoB,
    unsigned short* __restrict__ Qh, unsigned short* __restrict__ Kh,
    unsigned short* __restrict__ VtG)
{
    const int t = threadIdx.x;
    const int bid = blockIdx.x;
    if (bid >= 1536) {                     // fused Wo conversion tail (256 blocks)
        int i = (bid - 1536) * 1024 + t * 4;
        float4 f = *(const float4*)(Wo + i);
        short4v s;
        s[0] = (short)bfr(f.x); s[1] = (short)bfr(f.y);
        s[2] = (short)bfr(f.z); s[3] = (short)bfr(f.w);
        *(short4v*)(WoB + i) = s;
        return;
    }

    __shared__ __align__(16) unsigned short Wl[64 * 72];   // 9 KB

    const int x   = bid / 512;             // 0=q,1=k,2=v
    const int r_  = bid - x * 512;
    const int bh  = r_ >> 4;
    const int stg = r_ & 15;               // 8 s-tiles per block
    const int b = bh >> 3, h = bh & 7;
    const int L = t & 63, w = t >> 6;
    const int c = L & 15, qd = L >> 4;

    const float* Wf     = (x == 0) ? Wq : (x == 1) ? Wk : Wv;
    const float* bias_p = (x == 0) ? bq : (x == 1) ? bk : bv;
    const float* X      = (x == 0) ? q  : (x == 1) ? k  : v;

    // ---- cooperative W stage: 16 floats/thread, fully coalesced ----
    {
        int base = t * 16;                 // row = t>>2, col = (t&3)*16
        int row = t >> 2, col = (t & 3) * 16;
        short8 s0 = cvt8(Wf + base);
        short8 s1 = cvt8(Wf + base + 8);
        *(short8*)&Wl[row * 72 + col]     = s0;
        *(short8*)&Wl[row * 72 + col + 8] = s1;
    }
    __syncthreads();

    // ---- W fragments (read once per wave) + biases ----
    short8 wf[4][2];
    #pragma unroll
    for (int nt = 0; nt < 4; ++nt)
        #pragma unroll
        for (int kc = 0; kc < 2; ++kc)
            wf[nt][kc] = *(const short8*)&Wl[(16 * nt + c) * 72 + kc * 32 + 8 * qd];

    if (x < 2) {
        float bias[4];
        #pragma unroll
        for (int nt = 0; nt < 4; ++nt) bias[nt] = bias_p[16 * nt + c];
        const float sc = (x == 0) ? QSCALE : 1.0f;
        #pragma unroll
        for (int ti = 0; ti < 2; ++ti) {
            const int st = stg * 8 + w * 2 + ti;
            const float* xrow = X + ((size_t)(b * S + st * 16 + c)) * D + h * HD;
            short8 af0 = cvt8(xrow + 8 * qd);
            short8 af1 = cvt8(xrow + 32 + 8 * qd);
            f32x4 acc[4];
            #pragma unroll
            for (int nt = 0; nt < 4; ++nt) {
                acc[nt] = (f32x4){bias[nt], bias[nt], bias[nt], bias[nt]};
                acc[nt] = __builtin_amdgcn_mfma_f32_16x16x32_bf16(af0, wf[nt][0], acc[nt], 0, 0, 0);
                acc[nt] = __builtin_amdgcn_mfma_f32_16x16x32_bf16(af1, wf[nt][1], acc[nt], 0, 0, 0);
            }
            unsigned short* O = ((x == 0) ? Qh : Kh)
                              + ((size_t)(b * H + h) * S + st * 16) * HD;
            #pragma unroll
            for (int nt = 0; nt < 4; ++nt)
                #pragma unroll
                for (int r = 0; r < 4; ++r)
                    O[(4 * qd + r) * HD + 16 * nt + c] = bfr(acc[nt][r] * sc);
        }
    } else {
        f32x4 bias4[4];
        #pragma unroll
        for (int nt = 0; nt < 4; ++nt) {
            float4 bb4 = *(const float4*)(bias_p + 16 * nt + 4 * qd);
            bias4[nt] = (f32x4){bb4.x, bb4.y, bb4.z, bb4.w};
        }
        #pragma unroll
        for (int ti = 0; ti < 2; ++ti) {
            const int st = stg * 8 + w * 2 + ti;
            const float* xrow = X + ((size_t)(b * S + st * 16 + c)) * D + h * HD;
            short8 af0 = cvt8(xrow + 8 * qd);
            short8 af1 = cvt8(xrow + 32 + 8 * qd);
            f32x4 acc[4];
            #pragma unroll
            for (int nt = 0; nt < 4; ++nt) {
                acc[nt] = bias4[nt];
                acc[nt] = __builtin_amdgcn_mfma_f32_16x16x32_bf16(wf[nt][0], af0, acc[nt], 0, 0, 0);
                acc[nt] = __builtin_amdgcn_mfma_f32_16x16x32_bf16(wf[nt][1], af1, acc[nt], 0, 0, 0);
            }
            unsigned short* O = VtG + (size_t)(b * H + h) * HD * S;
            #pragma unroll
            for (int nt = 0; nt < 4; ++nt)
                #pragma unroll
                for (int r = 0; r < 4; ++r)
                    O[(size_t)(16 * nt + 4 * qd + r) * S + st * 16 + c] = bfr(acc[nt][r]);
        }
    }
}

// ---------------------------------------------------------------------------
// Kernel 2: MFMA flash attention (UNCHANGED from round 8: 54.6 us known-good).
// ---------------------------------------------------------------------------
__global__ __launch_bounds__(256, 4) void attn_kernel(
    const unsigned short* __restrict__ Qh, const unsigned short* __restrict__ Kh,
    const unsigned short* __restrict__ VtG, unsigned short* __restrict__ accPb,
    float* __restrict__ lP)
{
    __shared__ __align__(16) unsigned short Ks[2][4096];   // 16 KB
    __shared__ __align__(16) unsigned short Vs[2][4096];   // 16 KB

    const int idx = blockIdx.x;
    const int bh = idx & 31;               // XCD-locality swizzle
    const int rem = idx >> 5;
    const int qt = rem >> 1;
    const int ks = rem & 1;
    const int b = bh >> 3, h = bh & 7;
    const int t = threadIdx.x;
    const int w = t >> 6, L = t & 63;
    const int c = L & 15, qd = L >> 4;

    const unsigned short* Kb = Kh + ((size_t)bh * S + ks * 1024) * HD;
    const unsigned short* Vb = VtG + (size_t)bh * HD * S + ks * 1024;

    short8 qf[2][2];
    #pragma unroll
    for (int qg = 0; qg < 2; ++qg)
        #pragma unroll
        for (int kc = 0; kc < 2; ++kc)
            qf[qg][kc] = *(const short8*)(Qh
                + ((size_t)bh * S + qt * 128 + w * 32 + qg * 16 + c) * HD
                + kc * 32 + 8 * qd);

    f32x4 acc[2][4];
    float lrun[2] = {0.f, 0.f};
    #pragma unroll
    for (int qg = 0; qg < 2; ++qg)
        #pragma unroll
        for (int dt = 0; dt < 4; ++dt) acc[qg][dt] = (f32x4){0.f, 0.f, 0.f, 0.f};

    const int sd = t >> 3, sj = t & 7;
    const int sp = sj >> 2, smt = (sj >> 1) & 1;
    const int sqa = (2 * sj) & 3, sqb = (2 * sj + 1) & 3;

    int4v vpre[2];
    #pragma unroll
    for (int i = 0; i < 2; ++i) {
        int bi = w + 4 * i;
        gl_lds16(Kb + (size_t)(16 * (bi >> 1) + c) * HD + (bi & 1) * 32 + qd * 8,
                 &Ks[0][bi * 512]);
        vpre[i] = *(const int4v*)(Vb + (size_t)(sd + 32 * i) * S + 8 * sj);
    }

    for (int it = 0; it < 16; ++it) {
        const int cur = it & 1, nxt = cur ^ 1;
        #pragma unroll
        for (int i = 0; i < 2; ++i) {
            int d = sd + 32 * i;
            int dt = d >> 4, cc = d & 15;
            union { int4v v; short4v h[2]; } u; u.v = vpre[i];
            *(short4v*)&Vs[cur][((dt * 2 + sp) * 64 + sqa * 16 + cc) * 8 + smt * 4] = u.h[0];
            *(short4v*)&Vs[cur][((dt * 2 + sp) * 64 + sqb * 16 + cc) * 8 + smt * 4] = u.h[1];
        }
        __syncthreads();
        if (it + 1 < 16) {
            int n1 = (it + 1) * 64;
            #pragma unroll
            for (int i = 0; i < 2; ++i) {
                int bi = w + 4 * i;
                gl_lds16(Kb + (size_t)(n1 + 16 * (bi >> 1) + c) * HD + (bi & 1) * 32 + qd * 8,
                         &Ks[nxt][bi * 512]);
                vpre[i] = *(const int4v*)(Vb + (size_t)(sd + 32 * i) * S + n1 + 8 * sj);
            }
        }

        const unsigned short* KsC = Ks[cur];
        const unsigned short* VsC = Vs[cur];

        short4v pa[2][4];
        #pragma unroll
        for (int mt = 0; mt < 4; ++mt) {
            short8 a0 = *(const short8*)(KsC + (mt * 2 + 0) * 512 + L * 8);
            short8 a1 = *(const short8*)(KsC + (mt * 2 + 1) * 512 + L * 8);
            #pragma unroll
            for (int qg = 0; qg < 2; ++qg) {
                f32x4 stv = (f32x4){-MFIX, -MFIX, -MFIX, -MFIX};
                stv = __builtin_amdgcn_mfma_f32_16x16x32_bf16(a0, qf[qg][0], stv, 0, 0, 0);
                stv = __builtin_amdgcn_mfma_f32_16x16x32_bf16(a1, qf[qg][1], stv, 0, 0, 0);
                float p0 = ex2(stv[0]), p1 = ex2(stv[1]);
                float p2 = ex2(stv[2]), p3 = ex2(stv[3]);
                lrun[qg] += (p0 + p1) + (p2 + p3);
                short4v p_;
                p_[0] = (short)bfr(p0); p_[1] = (short)bfr(p1);
                p_[2] = (short)bfr(p2); p_[3] = (short)bfr(p3);
                pa[qg][mt] = p_;
            }
        }

        #pragma unroll
        for (int dt = 0; dt < 4; ++dt)
            #pragma unroll
            for (int p = 0; p < 2; ++p) {
                union { short8 v8; short4v h[2]; } u;
                u.v8 = *(const short8*)(VsC + (dt * 2 + p) * 512 + L * 8);
#if __has_builtin(__builtin_amdgcn_mfma_f32_16x16x16bf16_1k)
                #pragma unroll
                for (int qg = 0; qg < 2; ++qg) {
                    acc[qg][dt] = __builtin_amdgcn_mfma_f32_16x16x16bf16_1k(
                        pa[qg][2 * p + 0], u.h[0], acc[qg][dt], 0, 0, 0);
                    acc[qg][dt] = __builtin_amdgcn_mfma_f32_16x16x16bf16_1k(
                        pa[qg][2 * p + 1], u.h[1], acc[qg][dt], 0, 0, 0);
                }
#else
                #pragma unroll
                for (int qg = 0; qg < 2; ++qg) {
                    short8 pz0 = {pa[qg][2 * p + 0][0], pa[qg][2 * p + 0][1],
                                  pa[qg][2 * p + 0][2], pa[qg][2 * p + 0][3], 0, 0, 0, 0};
                    short8 pz1 = {pa[qg][2 * p + 1][0], pa[qg][2 * p + 1][1],
                                  pa[qg][2 * p + 1][2], pa[qg][2 * p + 1][3], 0, 0, 0, 0};
                    short8 v0 = {u.h[0][0], u.h[0][1], u.h[0][2], u.h[0][3], 0, 0, 0, 0};
                    short8 v1 = {u.h[1][0], u.h[1][1], u.h[1][2], u.h[1][3], 0, 0, 0, 0};
                    acc[qg][dt] = __builtin_amdgcn_mfma_f32_16x16x32_bf16(pz0, v0, acc[qg][dt], 0, 0, 0);
                    acc[qg][dt] = __builtin_amdgcn_mfma_f32_16x16x32_bf16(pz1, v1, acc[qg][dt], 0, 0, 0);
                }
#endif
            }
    }

    const int q0 = qt * 128 + w * 32;
    unsigned short* accPp = accPb + (size_t)ks * ((size_t)B * S * D)
                          + ((size_t)b * S + q0) * D + h * HD;
    #pragma unroll
    for (int qg = 0; qg < 2; ++qg) {
        float lr = lrun[qg];
        lr += __shfl_xor(lr, 16);
        lr += __shfl_xor(lr, 32);
        if (qd == 0)
            lP[(size_t)ks * ((size_t)B * H * S) + (size_t)bh * S + q0 + qg * 16 + c] = lr;
        #pragma unroll
        for (int dt = 0; dt < 4; ++dt)
            #pragma unroll
            for (int r = 0; r < 4; ++r)
                accPp[(size_t)(qg * 16 + 4 * qd + r) * D + 16 * dt + c]
                    = bfr(acc[qg][dt][r]);
    }
}

// ---------------------------------------------------------------------------
// Kernel 3: split-K merge + output projection + LN + residual.
// 256 blocks x 1024 thr: 32 rows/block, 16 waves x 32-col strips.
// WoB fragments reused across 2 m-tiles (halves L2 B-traffic); exactly
// 1 block/CU, 4 waves/SIMD.
// ---------------------------------------------------------------------------
__global__ __launch_bounds__(1024) void oproj_ln_kernel(
    const unsigned short* __restrict__ accPb, const float* __restrict__ lP,
    const unsigned short* __restrict__ WoB,
    const float* __restrict__ bo, const float* __restrict__ gamma,
    const float* __restrict__ beta, const float* __restrict__ qin,
    float* __restrict__ out)
{
    __shared__ __align__(16) unsigned short As[32 * 520];  // 33.3 KB
    __shared__ float red[2][32][17];                       // 4.25 KB
    __shared__ float linv_s[32][8];
    __shared__ float mu_s2[32], rs_s2[32];

    const int t = threadIdx.x;             // 0..1023
    const int r0 = blockIdx.x * 32;
    const int w = t >> 6, L = t & 63;
    const int c = L & 15, qd = L >> 4;
    const int n0 = w * 32;
    const size_t NEh = (size_t)B * S * D;
    const size_t BHS = (size_t)B * H * S;

    if (t < 256) {                         // 1/(l0+l1) per (row, head)
        int row = t >> 3, hh = t & 7;
        int bb = r0 >> 11;
        int ss = (r0 & (S - 1)) + row;
        float l0 = lP[(size_t)(bb * H + hh) * S + ss];
        float l1 = lP[BHS + (size_t)(bb * H + hh) * S + ss];
        linv_s[row][hh] = 1.f / (l0 + l1);
    }
    __syncthreads();

    // stage merged A (bf16): 32 rows x 512 cols
    #pragma unroll
    for (int i = 0; i < 4; ++i) {
        int flat = t + 1024 * i;
        int row = flat >> 7, cg = flat & 127;
        int col = cg * 4;
        size_t gi = (size_t)(r0 + row) * D + col;
        short4v a0 = *(const short4v*)(accPb + gi);
        short4v a1 = *(const short4v*)(accPb + NEh + gi);
        float li = linv_s[row][col >> 6];
        short4v s;
        #pragma unroll
        for (int j = 0; j < 4; ++j)
            s[j] = (short)bfr((b2f((unsigned short)a0[j])
                             + b2f((unsigned short)a1[j])) * li);
        *(short4v*)&As[row * 520 + col] = s;
    }
    __syncthreads();

    f32x4 acc[2][2];
    #pragma unroll
    for (int nt = 0; nt < 2; ++nt) {
        float bv_ = bo[n0 + 16 * nt + c];
        acc[0][nt] = (f32x4){bv_, bv_, bv_, bv_};
        acc[1][nt] = (f32x4){bv_, bv_, bv_, bv_};
    }

    for (int kc = 0; kc < 16; ++kc) {
        short8 a0 = *(const short8*)&As[c * 520 + kc * 32 + 8 * qd];
        short8 a1 = *(const short8*)&As[(16 + c) * 520 + kc * 32 + 8 * qd];
        #pragma unroll
        for (int nt = 0; nt < 2; ++nt) {
            short8 bf = *(const short8*)(WoB + (size_t)(n0 + 16 * nt + c) * D
                                         + kc * 32 + 8 * qd);
            acc[0][nt] = __builtin_amdgcn_mfma_f32_16x16x32_bf16(a0, bf, acc[0][nt], 0, 0, 0);
            acc[1][nt] = __builtin_amdgcn_mfma_f32_16x16x32_bf16(a1, bf, acc[1][nt], 0, 0, 0);
        }
    }

    // LN stats: in-lane over nt, shuffle over c, two-stage LDS over 16 waves
    float sm[2][4], sq[2][4];
    #pragma unroll
    for (int mt = 0; mt < 2; ++mt)
        #pragma unroll
        for (int r = 0; r < 4; ++r) { sm[mt][r] = 0.f; sq[mt][r] = 0.f; }
    #pragma unroll
    for (int mt = 0; mt < 2; ++mt)
        #pragma unroll
        for (int nt = 0; nt < 2; ++nt)
            #pragma unroll
            for (int r = 0; r < 4; ++r) {
                float x_ = acc[mt][nt][r];
                sm[mt][r] += x_; sq[mt][r] += x_ * x_;
            }
    #pragma unroll
    for (int mask = 1; mask <= 8; mask <<= 1)
        #pragma unroll
        for (int mt = 0; mt < 2; ++mt)
            #pragma unroll
            for (int r = 0; r < 4; ++r) {
                sm[mt][r] += __shfl_xor(sm[mt][r], mask);
                sq[mt][r] += __shfl_xor(sq[mt][r], mask);
            }
    if (c == 0) {
        #pragma unroll
        for (int mt = 0; mt < 2; ++mt)
            #pragma unroll
            for (int r = 0; r < 4; ++r) {
                red[0][mt * 16 + 4 * qd + r][w] = sm[mt][r];
                red[1][mt * 16 + 4 * qd + r][w] = sq[mt][r];
            }
    }
    __syncthreads();

    if (t < 32) {                          // final reduce over 16 waves
        float s_ = 0.f, q_ = 0.f;
        #pragma unroll
        for (int w_ = 0; w_ < 16; ++w_) { s_ += red[0][t][w_]; q_ += red[1][t][w_]; }
        float mu_ = s_ * (1.f / D);
        float var = q_ * (1.f / D) - mu_ * mu_;    // population var (jnp.var)
        mu_s2[t] = mu_;
        rs_s2[t] = rsqrtf(var + 1e-5f);
    }
    __syncthreads();

    #pragma unroll
    for (int nt = 0; nt < 2; ++nt) {
        int n = n0 + 16 * nt + c;
        float g = gamma[n], be = beta[n];
        #pragma unroll
        for (int mt = 0; mt < 2; ++mt)
            #pragma unroll
            for (int r = 0; r < 4; ++r) {
                int m = mt * 16 + 4 * qd + r;
                size_t gi = (size_t)(r0 + m) * D + n;
                out[gi] = qin[gi] + (acc[mt][nt][r] - mu_s2[m]) * rs_s2[m] * g + be;
            }
    }
}

// ---------------------------------------------------------------------------
extern "C" void kernel_launch(void* const* d_in, const int* in_sizes, int n_in,
                              void* d_out, int out_size, void* d_ws, size_t ws_size,
                              hipStream_t stream) {
    const float* q     = (const float*)d_in[0];
    const float* k     = (const float*)d_in[1];
    const float* v     = (const float*)d_in[2];
    const float* Wq    = (const float*)d_in[3];
    const float* bq    = (const float*)d_in[4];
    const float* Wk    = (const float*)d_in[5];
    const float* bk    = (const float*)d_in[6];
    const float* Wv    = (const float*)d_in[7];
    const float* bv    = (const float*)d_in[8];
    const float* Wo    = (const float*)d_in[9];
    const float* bo    = (const float*)d_in[10];
    const float* gamma = (const float*)d_in[11];
    const float* beta  = (const float*)d_in[12];
    float* out = (float*)d_out;

    const size_t NE = (size_t)B * S * D;          // 4,194,304
    unsigned short* wsu = (unsigned short*)d_ws;
    unsigned short* Qh    = wsu;                  // bf16 [B,H,S,HD]   8 MB
    unsigned short* Kh    = wsu + NE;             // bf16 [B,H,S,HD]   8 MB
    unsigned short* VtG   = wsu + 2 * NE;         // bf16 [B,H,HD,S]   8 MB
    unsigned short* WoB   = wsu + 3 * NE;         // bf16 [D,D]      0.5 MB
    unsigned short* accPb = WoB + (size_t)D * D;  // bf16 [2][B,S,D]  16 MB
    float* lP = (float*)(accPb + 2 * NE);         // f32 [2][B,H,S]  0.5 MB

    hipLaunchKernelGGL(qkv_mfma_kernel, dim3(1536 + 256), dim3(256), 0, stream,
                       q, k, v, Wq, bq, Wk, bk, Wv, bv, Wo, WoB, Qh, Kh, VtG);
    hipLaunchKernelGGL(attn_kernel, dim3(1024), dim3(256), 0, stream,
                       Qh, Kh, VtG, accPb, lP);
    hipLaunchKernelGGL(oproj_ln_kernel, dim3(B * S / 32), dim3(1024), 0, stream,
                       accPb, lP, WoB, bo, gamma, beta, q, out);
}

// Round 11
// 190.690 us; speedup vs baseline: 1.2441x; 1.0094x over previous
//
#include <hip/hip_runtime.h>
#include <hip/hip_cooperative_groups.h>
#include <hip/hip_bf16.h>
#include <math.h>
#include <stdint.h>

namespace cg = cooperative_groups;

#define B 4
#define S 2048
#define D 512
#define H 8
#define HD 64

typedef __attribute__((ext_vector_type(4))) int   int4v;
typedef __attribute__((ext_vector_type(8))) short short8;
typedef __attribute__((ext_vector_type(4))) short short4v;
typedef __attribute__((ext_vector_type(4))) float f32x4;

__device__ __forceinline__ unsigned short bfr(float x) {
    __bf16 h = (__bf16)x;
    union { __bf16 b; unsigned short s; } u; u.b = h; return u.s;
}
__device__ __forceinline__ float b2f(unsigned short s) {
    union { unsigned u; float f; } v; v.u = (unsigned)s << 16; return v.f;
}
__device__ __forceinline__ float ex2(float x) {
#if __has_builtin(__builtin_amdgcn_exp2f)
    return __builtin_amdgcn_exp2f(x);
#else
    return exp2f(x);
#endif
}
__device__ __forceinline__ short8 cvt8(const float* p) {
    float4 f0 = *(const float4*)p;
    float4 f1 = *(const float4*)(p + 4);
    short8 s8;
    s8[0] = (short)bfr(f0.x); s8[1] = (short)bfr(f0.y);
    s8[2] = (short)bfr(f0.z); s8[3] = (short)bfr(f0.w);
    s8[4] = (short)bfr(f1.x); s8[5] = (short)bfr(f1.y);
    s8[6] = (short)bfr(f1.z); s8[7] = (short)bfr(f1.w);
    return s8;
}

// log2e / sqrt(512): folded into Qh at projection time
#define QSCALE 0.06377229601488305f
// fixed log2-domain softmax max (scores |z| <~ 1; exact for any M). With
// k-split this makes partial (acc, l) sums EXACTLY mergeable by addition.
#define MFIX 4.0f

typedef const __attribute__((address_space(1))) unsigned char g8_t;
typedef __attribute__((address_space(3))) unsigned char l8_t;
__device__ __forceinline__ void gl_lds16(const unsigned short* g, unsigned short* l) {
#if __has_builtin(__builtin_amdgcn_global_load_lds)
    __builtin_amdgcn_global_load_lds((g8_t*)g, (l8_t*)l, 16, 0, 0);
#else
    int lane = threadIdx.x & 63;
    ((int4v*)l)[lane] = *(const int4v*)g;
#endif
}

// ===========================================================================
// FUSED cooperative kernel: 1024 blocks x 256 thr, static LDS = 16 KB
// (4 blocks/CU even under a 64 KB occupancy model).
// phase1 QKV -> grid.sync -> phase2 attn (V frags from L2) -> grid.sync
// -> phase3 merge+oproj+LN.
// ===========================================================================
__global__ __launch_bounds__(256, 4) void fused_kernel(
    const float* __restrict__ q, const float* __restrict__ k,
    const float* __restrict__ v,
    const float* __restrict__ Wq, const float* __restrict__ bq,
    const float* __restrict__ Wk, const float* __restrict__ bk,
    const float* __restrict__ Wv, const float* __restrict__ bv,
    const float* __restrict__ Wo, const float* __restrict__ bo,
    const float* __restrict__ gamma, const float* __restrict__ beta,
    unsigned short* __restrict__ Qh, unsigned short* __restrict__ Kh,
    unsigned short* __restrict__ VtG, unsigned short* __restrict__ WoB,
    unsigned short* __restrict__ accPb, float* __restrict__ lP,
    float* __restrict__ out)
{
    __shared__ __align__(16) unsigned char smem[16384];

    const int bid = blockIdx.x;
    const int t = threadIdx.x;
    const int w = t >> 6, L = t & 63;
    const int c = L & 15, qd = L >> 4;
    const size_t NEh = (size_t)B * S * D;
    const size_t BHS = (size_t)B * H * S;

    // ======================= PHASE 1: QKV projection =======================
    {
        int wi = bid * 256 + t;            // distributed Wo -> bf16
        WoB[wi] = bfr(Wo[wi]);

        const int bh = bid & 31;           // same XCD mapping as phase 2
        const int sg = bid >> 5;
        const int b = bh >> 3, h = bh & 7;
        const int st = sg * 4 + w;
        unsigned short* Wl = (unsigned short*)smem;   // 64x72 halves = 9 KB

        const float* Wsrc[3]  = {Wq, Wk, Wv};
        const float* biasP[3] = {bq, bk, bv};
        const float* Xs[3]    = {q, k, v};

        for (int x = 0; x < 3; ++x) {
            __syncthreads();
            {   // stage W_x fp32 -> bf16, coalesced
                int row = t >> 2, col = (t & 3) * 16;
                *(short8*)&Wl[row * 72 + col]     = cvt8(Wsrc[x] + t * 16);
                *(short8*)&Wl[row * 72 + col + 8] = cvt8(Wsrc[x] + t * 16 + 8);
            }
            __syncthreads();

            short8 wf[4][2];
            #pragma unroll
            for (int nt = 0; nt < 4; ++nt)
                #pragma unroll
                for (int kc = 0; kc < 2; ++kc)
                    wf[nt][kc] = *(const short8*)&Wl[(16 * nt + c) * 72 + kc * 32 + 8 * qd];

            const float* xrow = Xs[x] + ((size_t)(b * S + st * 16 + c)) * D + h * HD;
            short8 af0 = cvt8(xrow + 8 * qd);
            short8 af1 = cvt8(xrow + 32 + 8 * qd);

            if (x < 2) {
                f32x4 acc[4];
                #pragma unroll
                for (int nt = 0; nt < 4; ++nt) {
                    float bv_ = biasP[x][16 * nt + c];
                    acc[nt] = (f32x4){bv_, bv_, bv_, bv_};
                    acc[nt] = __builtin_amdgcn_mfma_f32_16x16x32_bf16(af0, wf[nt][0], acc[nt], 0, 0, 0);
                    acc[nt] = __builtin_amdgcn_mfma_f32_16x16x32_bf16(af1, wf[nt][1], acc[nt], 0, 0, 0);
                }
                unsigned short* O = ((x == 0) ? Qh : Kh)
                                  + ((size_t)(b * H + h) * S + st * 16) * HD;
                const float sc = (x == 0) ? QSCALE : 1.0f;
                #pragma unroll
                for (int nt = 0; nt < 4; ++nt)
                    #pragma unroll
                    for (int r = 0; r < 4; ++r)
                        O[(4 * qd + r) * HD + 16 * nt + c] = bfr(acc[nt][r] * sc);
            } else {
                // V^T directly: A = Wv (m=d), B = x^T (n=s); C row=d, col=s
                f32x4 acc[4];
                #pragma unroll
                for (int nt = 0; nt < 4; ++nt) {
                    float4 bb4 = *(const float4*)(biasP[x] + 16 * nt + 4 * qd);
                    acc[nt] = (f32x4){bb4.x, bb4.y, bb4.z, bb4.w};
                    acc[nt] = __builtin_amdgcn_mfma_f32_16x16x32_bf16(wf[nt][0], af0, acc[nt], 0, 0, 0);
                    acc[nt] = __builtin_amdgcn_mfma_f32_16x16x32_bf16(wf[nt][1], af1, acc[nt], 0, 0, 0);
                }
                unsigned short* O = VtG + (size_t)(b * H + h) * HD * S;
                #pragma unroll
                for (int nt = 0; nt < 4; ++nt)
                    #pragma unroll
                    for (int r = 0; r < 4; ++r)
                        O[(size_t)(16 * nt + 4 * qd + r) * S + st * 16 + c] = bfr(acc[nt][r]);
            }
        }
    }

    cg::this_grid().sync();

    // ======================= PHASE 2: flash attention ======================
    {
        unsigned short (*Ks)[4096] = (unsigned short (*)[4096])smem;  // 16 KB

        const int bh = bid & 31;
        const int rem = bid >> 5;
        const int qt = rem >> 1;
        const int ks = rem & 1;
        const int b = bh >> 3, h = bh & 7;

        const unsigned short* Kb = Kh + ((size_t)bh * S + ks * 1024) * HD;
        const unsigned short* Vb = VtG + (size_t)bh * HD * S + ks * 1024;

        short8 qf[2][2];
        #pragma unroll
        for (int qg = 0; qg < 2; ++qg)
            #pragma unroll
            for (int kc = 0; kc < 2; ++kc)
                qf[qg][kc] = *(const short8*)(Qh
                    + ((size_t)bh * S + qt * 128 + w * 32 + qg * 16 + c) * HD
                    + kc * 32 + 8 * qd);

        f32x4 acc[2][4];
        float lrun[2] = {0.f, 0.f};
        #pragma unroll
        for (int qg = 0; qg < 2; ++qg)
            #pragma unroll
            for (int dt = 0; dt < 4; ++dt) acc[qg][dt] = (f32x4){0.f, 0.f, 0.f, 0.f};

        // K staging (r8-verified fragment-order gl_lds, double-buffered)
        #pragma unroll
        for (int i = 0; i < 2; ++i) {
            int bi = w + 4 * i;
            gl_lds16(Kb + (size_t)(16 * (bi >> 1) + c) * HD + (bi & 1) * 32 + qd * 8,
                     &Ks[0][bi * 512]);
        }

        for (int it = 0; it < 16; ++it) {
            const int cur = it & 1;
            __syncthreads();
            if (it + 1 < 16) {
                int n1 = (it + 1) * 64;
                #pragma unroll
                for (int i = 0; i < 2; ++i) {
                    int bi = w + 4 * i;
                    gl_lds16(Kb + (size_t)(n1 + 16 * (bi >> 1) + c) * HD + (bi & 1) * 32 + qd * 8,
                             &Ks[cur ^ 1][bi * 512]);
                }
            }
            const int n0 = it * 64;

            // V fragments straight from VtG (same-XCD L2-hot), reused by both qg
            short4v vf[4][4];
            #pragma unroll
            for (int dt = 0; dt < 4; ++dt)
                #pragma unroll
                for (int mt = 0; mt < 4; ++mt)
                    vf[dt][mt] = *(const short4v*)(Vb + (size_t)(16 * dt + c) * S
                                                   + n0 + 16 * mt + 4 * qd);

            const unsigned short* KsC = Ks[cur];
            short4v pa[2][4];
            #pragma unroll
            for (int mt = 0; mt < 4; ++mt) {
                short8 a0 = *(const short8*)(KsC + (mt * 2 + 0) * 512 + L * 8);
                short8 a1 = *(const short8*)(KsC + (mt * 2 + 1) * 512 + L * 8);
                #pragma unroll
                for (int qg = 0; qg < 2; ++qg) {
                    f32x4 stv = (f32x4){-MFIX, -MFIX, -MFIX, -MFIX};
                    stv = __builtin_amdgcn_mfma_f32_16x16x32_bf16(a0, qf[qg][0], stv, 0, 0, 0);
                    stv = __builtin_amdgcn_mfma_f32_16x16x32_bf16(a1, qf[qg][1], stv, 0, 0, 0);
                    float p0 = ex2(stv[0]), p1 = ex2(stv[1]);
                    float p2 = ex2(stv[2]), p3 = ex2(stv[3]);
                    lrun[qg] += (p0 + p1) + (p2 + p3);
                    short4v p_;
                    p_[0] = (short)bfr(p0); p_[1] = (short)bfr(p1);
                    p_[2] = (short)bfr(p2); p_[3] = (short)bfr(p3);
                    pa[qg][mt] = p_;
                }
            }

            #pragma unroll
            for (int dt = 0; dt < 4; ++dt)
                #pragma unroll
                for (int mt = 0; mt < 4; ++mt) {
#if __has_builtin(__builtin_amdgcn_mfma_f32_16x16x16bf16_1k)
                    #pragma unroll
                    for (int qg = 0; qg < 2; ++qg)
                        acc[qg][dt] = __builtin_amdgcn_mfma_f32_16x16x16bf16_1k(
                            pa[qg][mt], vf[dt][mt], acc[qg][dt], 0, 0, 0);
#else
                    #pragma unroll
                    for (int qg = 0; qg < 2; ++qg) {
                        short8 pz = {pa[qg][mt][0], pa[qg][mt][1],
                                     pa[qg][mt][2], pa[qg][mt][3], 0, 0, 0, 0};
                        short8 vz = {vf[dt][mt][0], vf[dt][mt][1],
                                     vf[dt][mt][2], vf[dt][mt][3], 0, 0, 0, 0};
                        acc[qg][dt] = __builtin_amdgcn_mfma_f32_16x16x32_bf16(pz, vz, acc[qg][dt], 0, 0, 0);
                    }
#endif
                }
        }

        const int q0 = qt * 128 + w * 32;
        unsigned short* accPp = accPb + (size_t)ks * NEh
                              + ((size_t)b * S + q0) * D + h * HD;
        #pragma unroll
        for (int qg = 0; qg < 2; ++qg) {
            float lr = lrun[qg];
            lr += __shfl_xor(lr, 16);
            lr += __shfl_xor(lr, 32);
            if (qd == 0)
                lP[(size_t)ks * BHS + (size_t)bh * S + q0 + qg * 16 + c] = lr;
            #pragma unroll
            for (int dt = 0; dt < 4; ++dt)
                #pragma unroll
                for (int r = 0; r < 4; ++r)
                    accPp[(size_t)(qg * 16 + 4 * qd + r) * D + 16 * dt + c]
                        = bfr(acc[qg][dt][r]);
        }
    }

    cg::this_grid().sync();

    // ================== PHASE 3: merge + oproj + LN + residual =============
    if (bid < 512) {
        unsigned short* As = (unsigned short*)smem;  // stride 512, XOR-swizzle: 16384 B

        const int r0 = bid * 16;
        const int n0 = w * 128;
        const int bb = r0 >> 11;

        // stage merged A (bf16), inline l-merge; swizzled chunk placement
        #pragma unroll
        for (int i = 0; i < 8; ++i) {
            int flat = t + 256 * i;
            int row = flat >> 7, cg4 = flat & 127;
            int col = cg4 * 4;
            size_t gi = (size_t)(r0 + row) * D + col;
            short4v a0 = *(const short4v*)(accPb + gi);
            short4v a1 = *(const short4v*)(accPb + NEh + gi);
            int hh = col >> 6, ss = (r0 & (S - 1)) + row;
            float l0 = lP[(size_t)(bb * H + hh) * S + ss];
            float l1 = lP[BHS + (size_t)(bb * H + hh) * S + ss];
            float li = 1.f / (l0 + l1);
            short4v s;
            #pragma unroll
            for (int j = 0; j < 4; ++j)
                s[j] = (short)bfr((b2f((unsigned short)a0[j])
                                 + b2f((unsigned short)a1[j])) * li);
            int chunk8 = cg4 >> 1;
            *(short4v*)&As[row * 512 + ((chunk8 ^ (row & 7)) << 3) + (cg4 & 1) * 4] = s;
        }
        __syncthreads();

        f32x4 acc[8];
        #pragma unroll
        for (int nt = 0; nt < 8; ++nt) {
            float bv_ = bo[n0 + 16 * nt + c];
            acc[nt] = (f32x4){bv_, bv_, bv_, bv_};
        }

        for (int kc = 0; kc < 16; ++kc) {
            short8 a0 = *(const short8*)&As[c * 512 + (((kc * 4 + qd) ^ (c & 7)) << 3)];
            #pragma unroll
            for (int nt = 0; nt < 8; ++nt) {
                short8 bf = *(const short8*)(WoB + (size_t)(n0 + 16 * nt + c) * D
                                             + kc * 32 + 8 * qd);
                acc[nt] = __builtin_amdgcn_mfma_f32_16x16x32_bf16(a0, bf, acc[nt], 0, 0, 0);
            }
        }
        __syncthreads();                   // As reads done; reuse smem for LN scratch

        float* red   = (float*)smem;       // [8][16] floats = 512 B
        float* mu_s2 = (float*)(smem + 2048);
        float* rs_s2 = (float*)(smem + 2048 + 64);

        float sm[4], sq[4];
        #pragma unroll
        for (int r = 0; r < 4; ++r) { sm[r] = 0.f; sq[r] = 0.f; }
        #pragma unroll
        for (int nt = 0; nt < 8; ++nt)
            #pragma unroll
            for (int r = 0; r < 4; ++r) {
                float x_ = acc[nt][r];
                sm[r] += x_; sq[r] += x_ * x_;
            }
        #pragma unroll
        for (int mask = 1; mask <= 8; mask <<= 1)
            #pragma unroll
            for (int r = 0; r < 4; ++r) {
                sm[r] += __shfl_xor(sm[r], mask);
                sq[r] += __shfl_xor(sq[r], mask);
            }
        if (c == 0) {
            #pragma unroll
            for (int r = 0; r < 4; ++r) {
                red[w * 16 + 4 * qd + r]       = sm[r];
                red[(4 + w) * 16 + 4 * qd + r] = sq[r];
            }
        }
        __syncthreads();

        if (t < 16) {
            float s_ = 0.f, q_ = 0.f;
            #pragma unroll
            for (int w_ = 0; w_ < 4; ++w_) {
                s_ += red[w_ * 16 + t];
                q_ += red[(4 + w_) * 16 + t];
            }
            float mu_ = s_ * (1.f / D);
            float var = q_ * (1.f / D) - mu_ * mu_;   // population var (jnp.var)
            mu_s2[t] = mu_;
            rs_s2[t] = rsqrtf(var + 1e-5f);
        }
        __syncthreads();

        #pragma unroll
        for (int nt = 0; nt < 8; ++nt) {
            int n = n0 + 16 * nt + c;
            float g = gamma[n], be = beta[n];
            #pragma unroll
            for (int r = 0; r < 4; ++r) {
                int m = 4 * qd + r;
                size_t gi = (size_t)(r0 + m) * D + n;
                out[gi] = q[gi] + (acc[nt][r] - mu_s2[m]) * rs_s2[m] * g + be;
            }
        }
    }
}

// ===========================================================================
// FALLBACK path: round-9 three-kernel pipeline (known-good, 192.5 us).
// ===========================================================================
__global__ __launch_bounds__(256) void qkv_mfma_kernel(
    const float* __restrict__ q, const float* __restrict__ k,
    const float* __restrict__ v,
    const float* __restrict__ Wq, const float* __restrict__ bq,
    const float* __restrict__ Wk, const float* __restrict__ bk,
    const float* __restrict__ Wv, const float* __restrict__ bv,
    const float* __restrict__ Wo, unsigned short* __restrict__ WoB,
    unsigned short* __restrict__ Qh, unsigned short* __restrict__ Kh,
    unsigned short* __restrict__ VtG)
{
    const int t = threadIdx.x;
    const int bid = blockIdx.x;
    if (bid >= 1536) {
        int i = (bid - 1536) * 1024 + t * 4;
        float4 f = *(const float4*)(Wo + i);
        short4v s;
        s[0] = (short)bfr(f.x); s[1] = (short)bfr(f.y);
        s[2] = (short)bfr(f.z); s[3] = (short)bfr(f.w);
        *(short4v*)(WoB + i) = s;
        return;
    }

    __shared__ __align__(16) unsigned short Wl[64 * 72];

    const int x   = bid / 512;
    const int r_  = bid - x * 512;
    const int bh  = r_ >> 4;
    const int stg = r_ & 15;
    const int b = bh >> 3, h = bh & 7;
    const int L = t & 63, w = t >> 6;
    const int c = L & 15, qd = L >> 4;

    const float* Wf     = (x == 0) ? Wq : (x == 1) ? Wk : Wv;
    const float* bias_p = (x == 0) ? bq : (x == 1) ? bk : bv;
    const float* X      = (x == 0) ? q  : (x == 1) ? k  : v;

    {
        int row = t >> 2, col = (t & 3) * 16;
        *(short8*)&Wl[row * 72 + col]     = cvt8(Wf + t * 16);
        *(short8*)&Wl[row * 72 + col + 8] = cvt8(Wf + t * 16 + 8);
    }
    __syncthreads();

    short8 wf[4][2];
    #pragma unroll
    for (int nt = 0; nt < 4; ++nt)
        #pragma unroll
        for (int kc = 0; kc < 2; ++kc)
            wf[nt][kc] = *(const short8*)&Wl[(16 * nt + c) * 72 + kc * 32 + 8 * qd];

    if (x < 2) {
        float bias[4];
        #pragma unroll
        for (int nt = 0; nt < 4; ++nt) bias[nt] = bias_p[16 * nt + c];
        const float sc = (x == 0) ? QSCALE : 1.0f;
        #pragma unroll
        for (int ti = 0; ti < 2; ++ti) {
            const int st = stg * 8 + w * 2 + ti;
            const float* xrow = X + ((size_t)(b * S + st * 16 + c)) * D + h * HD;
            short8 af0 = cvt8(xrow + 8 * qd);
            short8 af1 = cvt8(xrow + 32 + 8 * qd);
            f32x4 acc[4];
            #pragma unroll
            for (int nt = 0; nt < 4; ++nt) {
                acc[nt] = (f32x4){bias[nt], bias[nt], bias[nt], bias[nt]};
                acc[nt] = __builtin_amdgcn_mfma_f32_16x16x32_bf16(af0, wf[nt][0], acc[nt], 0, 0, 0);
                acc[nt] = __builtin_amdgcn_mfma_f32_16x16x32_bf16(af1, wf[nt][1], acc[nt], 0, 0, 0);
            }
            unsigned short* O = ((x == 0) ? Qh : Kh)
                              + ((size_t)(b * H + h) * S + st * 16) * HD;
            #pragma unroll
            for (int nt = 0; nt < 4; ++nt)
                #pragma unroll
                for (int r = 0; r < 4; ++r)
                    O[(4 * qd + r) * HD + 16 * nt + c] = bfr(acc[nt][r] * sc);
        }
    } else {
        f32x4 bias4[4];
        #pragma unroll
        for (int nt = 0; nt < 4; ++nt) {
            float4 bb4 = *(const float4*)(bias_p + 16 * nt + 4 * qd);
            bias4[nt] = (f32x4){bb4.x, bb4.y, bb4.z, bb4.w};
        }
        #pragma unroll
        for (int ti = 0; ti < 2; ++ti) {
            const int st = stg * 8 + w * 2 + ti;
            const float* xrow = X + ((size_t)(b * S + st * 16 + c)) * D + h * HD;
            short8 af0 = cvt8(xrow + 8 * qd);
            short8 af1 = cvt8(xrow + 32 + 8 * qd);
            f32x4 acc[4];
            #pragma unroll
            for (int nt = 0; nt < 4; ++nt) {
                acc[nt] = bias4[nt];
                acc[nt] = __builtin_amdgcn_mfma_f32_16x16x32_bf16(wf[nt][0], af0, acc[nt], 0, 0, 0);
                acc[nt] = __builtin_amdgcn_mfma_f32_16x16x32_bf16(wf[nt][1], af1, acc[nt], 0, 0, 0);
            }
            unsigned short* O = VtG + (size_t)(b * H + h) * HD * S;
            #pragma unroll
            for (int nt = 0; nt < 4; ++nt)
                #pragma unroll
                for (int r = 0; r < 4; ++r)
                    O[(size_t)(16 * nt + 4 * qd + r) * S + st * 16 + c] = bfr(acc[nt][r]);
        }
    }
}

__global__ __launch_bounds__(256, 4) void attn_kernel(
    const unsigned short* __restrict__ Qh, const unsigned short* __restrict__ Kh,
    const unsigned short* __restrict__ VtG, unsigned short* __restrict__ accPb,
    float* __restrict__ lP)
{
    __shared__ __align__(16) unsigned short Ks[2][4096];
    __shared__ __align__(16) unsigned short Vs[2][4096];

    const int idx = blockIdx.x;
    const int bh = idx & 31;
    const int rem = idx >> 5;
    const int qt = rem >> 1;
    const int ks = rem & 1;
    const int b = bh >> 3, h = bh & 7;
    const int t = threadIdx.x;
    const int w = t >> 6, L = t & 63;
    const int c = L & 15, qd = L >> 4;

    const unsigned short* Kb = Kh + ((size_t)bh * S + ks * 1024) * HD;
    const unsigned short* Vb = VtG + (size_t)bh * HD * S + ks * 1024;

    short8 qf[2][2];
    #pragma unroll
    for (int qg = 0; qg < 2; ++qg)
        #pragma unroll
        for (int kc = 0; kc < 2; ++kc)
            qf[qg][kc] = *(const short8*)(Qh
                + ((size_t)bh * S + qt * 128 + w * 32 + qg * 16 + c) * HD
                + kc * 32 + 8 * qd);

    f32x4 acc[2][4];
    float lrun[2] = {0.f, 0.f};
    #pragma unroll
    for (int qg = 0; qg < 2; ++qg)
        #pragma unroll
        for (int dt = 0; dt < 4; ++dt) acc[qg][dt] = (f32x4){0.f, 0.f, 0.f, 0.f};

    const int sd = t >> 3, sj = t & 7;
    const int sp = sj >> 2, smt = (sj >> 1) & 1;
    const int sqa = (2 * sj) & 3, sqb = (2 * sj + 1) & 3;

    int4v vpre[2];
    #pragma unroll
    for (int i = 0; i < 2; ++i) {
        int bi = w + 4 * i;
        gl_lds16(Kb + (size_t)(16 * (bi >> 1) + c) * HD + (bi & 1) * 32 + qd * 8,
                 &Ks[0][bi * 512]);
        vpre[i] = *(const int4v*)(Vb + (size_t)(sd + 32 * i) * S + 8 * sj);
    }

    for (int it = 0; it < 16; ++it) {
        const int cur = it & 1, nxt = cur ^ 1;
        #pragma unroll
        for (int i = 0; i < 2; ++i) {
            int d = sd + 32 * i;
            int dt = d >> 4, cc = d & 15;
            union { int4v v; short4v h[2]; } u; u.v = vpre[i];
            *(short4v*)&Vs[cur][((dt * 2 + sp) * 64 + sqa * 16 + cc) * 8 + smt * 4] = u.h[0];
            *(short4v*)&Vs[cur][((dt * 2 + sp) * 64 + sqb * 16 + cc) * 8 + smt * 4] = u.h[1];
        }
        __syncthreads();
        if (it + 1 < 16) {
            int n1 = (it + 1) * 64;
            #pragma unroll
            for (int i = 0; i < 2; ++i) {
                int bi = w + 4 * i;
                gl_lds16(Kb + (size_t)(n1 + 16 * (bi >> 1) + c) * HD + (bi & 1) * 32 + qd * 8,
                         &Ks[nxt][bi * 512]);
                vpre[i] = *(const int4v*)(Vb + (size_t)(sd + 32 * i) * S + n1 + 8 * sj);
            }
        }

        const unsigned short* KsC = Ks[cur];
        const unsigned short* VsC = Vs[cur];

        short4v pa[2][4];
        #pragma unroll
        for (int mt = 0; mt < 4; ++mt) {
            short8 a0 = *(const short8*)(KsC + (mt * 2 + 0) * 512 + L * 8);
            short8 a1 = *(const short8*)(KsC + (mt * 2 + 1) * 512 + L * 8);
            #pragma unroll
            for (int qg = 0; qg < 2; ++qg) {
                f32x4 stv = (f32x4){-MFIX, -MFIX, -MFIX, -MFIX};
                stv = __builtin_amdgcn_mfma_f32_16x16x32_bf16(a0, qf[qg][0], stv, 0, 0, 0);
                stv = __builtin_amdgcn_mfma_f32_16x16x32_bf16(a1, qf[qg][1], stv, 0, 0, 0);
                float p0 = ex2(stv[0]), p1 = ex2(stv[1]);
                float p2 = ex2(stv[2]), p3 = ex2(stv[3]);
                lrun[qg] += (p0 + p1) + (p2 + p3);
                short4v p_;
                p_[0] = (short)bfr(p0); p_[1] = (short)bfr(p1);
                p_[2] = (short)bfr(p2); p_[3] = (short)bfr(p3);
                pa[qg][mt] = p_;
            }
        }

        #pragma unroll
        for (int dt = 0; dt < 4; ++dt)
            #pragma unroll
            for (int p = 0; p < 2; ++p) {
                union { short8 v8; short4v h[2]; } u;
                u.v8 = *(const short8*)(VsC + (dt * 2 + p) * 512 + L * 8);
#if __has_builtin(__builtin_amdgcn_mfma_f32_16x16x16bf16_1k)
                #pragma unroll
                for (int qg = 0; qg < 2; ++qg) {
                    acc[qg][dt] = __builtin_amdgcn_mfma_f32_16x16x16bf16_1k(
                        pa[qg][2 * p + 0], u.h[0], acc[qg][dt], 0, 0, 0);
                    acc[qg][dt] = __builtin_amdgcn_mfma_f32_16x16x16bf16_1k(
                        pa[qg][2 * p + 1], u.h[1], acc[qg][dt], 0, 0, 0);
                }
#else
                #pragma unroll
                for (int qg = 0; qg < 2; ++qg) {
                    short8 pz0 = {pa[qg][2 * p + 0][0], pa[qg][2 * p + 0][1],
                                  pa[qg][2 * p + 0][2], pa[qg][2 * p + 0][3], 0, 0, 0, 0};
                    short8 pz1 = {pa[qg][2 * p + 1][0], pa[qg][2 * p + 1][1],
                                  pa[qg][2 * p + 1][2], pa[qg][2 * p + 1][3], 0, 0, 0, 0};
                    short8 v0 = {u.h[0][0], u.h[0][1], u.h[0][2], u.h[0][3], 0, 0, 0, 0};
                    short8 v1 = {u.h[1][0], u.h[1][1], u.h[1][2], u.h[1][3], 0, 0, 0, 0};
                    acc[qg][dt] = __builtin_amdgcn_mfma_f32_16x16x32_bf16(pz0, v0, acc[qg][dt], 0, 0, 0);
                    acc[qg][dt] = __builtin_amdgcn_mfma_f32_16x16x32_bf16(pz1, v1, acc[qg][dt], 0, 0, 0);
                }
#endif
            }
    }

    const int q0 = qt * 128 + w * 32;
    unsigned short* accPp = accPb + (size_t)ks * ((size_t)B * S * D)
                          + ((size_t)b * S + q0) * D + h * HD;
    #pragma unroll
    for (int qg = 0; qg < 2; ++qg) {
        float lr = lrun[qg];
        lr += __shfl_xor(lr, 16);
        lr += __shfl_xor(lr, 32);
        if (qd == 0)
            lP[(size_t)ks * ((size_t)B * H * S) + (size_t)bh * S + q0 + qg * 16 + c] = lr;
        #pragma unroll
        for (int dt = 0; dt < 4; ++dt)
            #pragma unroll
            for (int r = 0; r < 4; ++r)
                accPp[(size_t)(qg * 16 + 4 * qd + r) * D + 16 * dt + c]
                    = bfr(acc[qg][dt][r]);
    }
}

__global__ __launch_bounds__(1024) void oproj_ln_kernel(
    const unsigned short* __restrict__ accPb, const float* __restrict__ lP,
    const unsigned short* __restrict__ WoB,
    const float* __restrict__ bo, const float* __restrict__ gamma,
    const float* __restrict__ beta, const float* __restrict__ qin,
    float* __restrict__ out)
{
    __shared__ __align__(16) unsigned short As[32 * 520];
    __shared__ float red[2][32][17];
    __shared__ float linv_s[32][8];
    __shared__ float mu_s2[32], rs_s2[32];

    const int t = threadIdx.x;
    const int r0 = blockIdx.x * 32;
    const int w = t >> 6, L = t & 63;
    const int c = L & 15, qd = L >> 4;
    const int n0 = w * 32;
    const size_t NEh = (size_t)B * S * D;
    const size_t BHS = (size_t)B * H * S;

    if (t < 256) {
        int row = t >> 3, hh = t & 7;
        int bb = r0 >> 11;
        int ss = (r0 & (S - 1)) + row;
        float l0 = lP[(size_t)(bb * H + hh) * S + ss];
        float l1 = lP[BHS + (size_t)(bb * H + hh) * S + ss];
        linv_s[row][hh] = 1.f / (l0 + l1);
    }
    __syncthreads();

    #pragma unroll
    for (int i = 0; i < 4; ++i) {
        int flat = t + 1024 * i;
        int row = flat >> 7, cg4 = flat & 127;
        int col = cg4 * 4;
        size_t gi = (size_t)(r0 + row) * D + col;
        short4v a0 = *(const short4v*)(accPb + gi);
        short4v a1 = *(const short4v*)(accPb + NEh + gi);
        float li = linv_s[row][col >> 6];
        short4v s;
        #pragma unroll
        for (int j = 0; j < 4; ++j)
            s[j] = (short)bfr((b2f((unsigned short)a0[j])
                             + b2f((unsigned short)a1[j])) * li);
        *(short4v*)&As[row * 520 + col] = s;
    }
    __syncthreads();

    f32x4 acc[2][2];
    #pragma unroll
    for (int nt = 0; nt < 2; ++nt) {
        float bv_ = bo[n0 + 16 * nt + c];
        acc[0][nt] = (f32x4){bv_, bv_, bv_, bv_};
        acc[1][nt] = (f32x4){bv_, bv_, bv_, bv_};
    }

    for (int kc = 0; kc < 16; ++kc) {
        short8 a0 = *(const short8*)&As[c * 520 + kc * 32 + 8 * qd];
        short8 a1 = *(const short8*)&As[(16 + c) * 520 + kc * 32 + 8 * qd];
        #pragma unroll
        for (int nt = 0; nt < 2; ++nt) {
            short8 bf = *(const short8*)(WoB + (size_t)(n0 + 16 * nt + c) * D
                                         + kc * 32 + 8 * qd);
            acc[0][nt] = __builtin_amdgcn_mfma_f32_16x16x32_bf16(a0, bf, acc[0][nt], 0, 0, 0);
            acc[1][nt] = __builtin_amdgcn_mfma_f32_16x16x32_bf16(a1, bf, acc[1][nt], 0, 0, 0);
        }
    }

    float sm[2][4], sq[2][4];
    #pragma unroll
    for (int mt = 0; mt < 2; ++mt)
        #pragma unroll
        for (int r = 0; r < 4; ++r) { sm[mt][r] = 0.f; sq[mt][r] = 0.f; }
    #pragma unroll
    for (int mt = 0; mt < 2; ++mt)
        #pragma unroll
        for (int nt = 0; nt < 2; ++nt)
            #pragma unroll
            for (int r = 0; r < 4; ++r) {
                float x_ = acc[mt][nt][r];
                sm[mt][r] += x_; sq[mt][r] += x_ * x_;
            }
    #pragma unroll
    for (int mask = 1; mask <= 8; mask <<= 1)
        #pragma unroll
        for (int mt = 0; mt < 2; ++mt)
            #pragma unroll
            for (int r = 0; r < 4; ++r) {
                sm[mt][r] += __shfl_xor(sm[mt][r], mask);
                sq[mt][r] += __shfl_xor(sq[mt][r], mask);
            }
    if (c == 0) {
        #pragma unroll
        for (int mt = 0; mt < 2; ++mt)
            #pragma unroll
            for (int r = 0; r < 4; ++r) {
                red[0][mt * 16 + 4 * qd + r][w] = sm[mt][r];
                red[1][mt * 16 + 4 * qd + r][w] = sq[mt][r];
            }
    }
    __syncthreads();

    if (t < 32) {
        float s_ = 0.f, q_ = 0.f;
        #pragma unroll
        for (int w_ = 0; w_ < 16; ++w_) { s_ += red[0][t][w_]; q_ += red[1][t][w_]; }
        float mu_ = s_ * (1.f / D);
        float var = q_ * (1.f / D) - mu_ * mu_;
        mu_s2[t] = mu_;
        rs_s2[t] = rsqrtf(var + 1e-5f);
    }
    __syncthreads();

    #pragma unroll
    for (int nt = 0; nt < 2; ++nt) {
        int n = n0 + 16 * nt + c;
        float g = gamma[n], be = beta[n];
        #pragma unroll
        for (int mt = 0; mt < 2; ++mt)
            #pragma unroll
            for (int r = 0; r < 4; ++r) {
                int m = mt * 16 + 4 * qd + r;
                size_t gi = (size_t)(r0 + m) * D + n;
                out[gi] = qin[gi] + (acc[mt][nt][r] - mu_s2[m]) * rs_s2[m] * g + be;
            }
    }
}

// ---------------------------------------------------------------------------
extern "C" void kernel_launch(void* const* d_in, const int* in_sizes, int n_in,
                              void* d_out, int out_size, void* d_ws, size_t ws_size,
                              hipStream_t stream) {
    const float* q     = (const float*)d_in[0];
    const float* k     = (const float*)d_in[1];
    const float* v     = (const float*)d_in[2];
    const float* Wq    = (const float*)d_in[3];
    const float* bq    = (const float*)d_in[4];
    const float* Wk    = (const float*)d_in[5];
    const float* bk    = (const float*)d_in[6];
    const float* Wv    = (const float*)d_in[7];
    const float* bv    = (const float*)d_in[8];
    const float* Wo    = (const float*)d_in[9];
    const float* bo    = (const float*)d_in[10];
    const float* gamma = (const float*)d_in[11];
    const float* beta  = (const float*)d_in[12];
    float* out = (float*)d_out;

    const size_t NE = (size_t)B * S * D;
    unsigned short* wsu = (unsigned short*)d_ws;
    unsigned short* Qh    = wsu;
    unsigned short* Kh    = wsu + NE;
    unsigned short* VtG   = wsu + 2 * NE;
    unsigned short* WoB   = wsu + 3 * NE;
    unsigned short* accPb = WoB + (size_t)D * D;
    float* lP = (float*)(accPb + 2 * NE);

    // deterministic per-call: occupancy query decides the path every time
    int maxB = 0;
    hipError_t qe = hipOccupancyMaxActiveBlocksPerMultiprocessor(
        &maxB, (const void*)fused_kernel, 256, 0);
    bool coop = (qe == hipSuccess && maxB >= 4);

    if (coop) {
        void* args[] = {
            (void*)&q, (void*)&k, (void*)&v,
            (void*)&Wq, (void*)&bq, (void*)&Wk, (void*)&bk, (void*)&Wv, (void*)&bv,
            (void*)&Wo, (void*)&bo, (void*)&gamma, (void*)&beta,
            (void*)&Qh, (void*)&Kh, (void*)&VtG, (void*)&WoB,
            (void*)&accPb, (void*)&lP, (void*)&out
        };
        hipError_t rc = hipLaunchCooperativeKernel((const void*)fused_kernel,
                                                   dim3(1024), dim3(256),
                                                   args, 0, stream);
        if (rc != hipSuccess) coop = false;
    }

    if (!coop) {   // round-9 known-good pipeline
        hipLaunchKernelGGL(qkv_mfma_kernel, dim3(1536 + 256), dim3(256), 0, stream,
                           q, k, v, Wq, bq, Wk, bk, Wv, bv, Wo, WoB, Qh, Kh, VtG);
        hipLaunchKernelGGL(attn_kernel, dim3(1024), dim3(256), 0, stream,
                           Qh, Kh, VtG, accPb, lP);
        hipLaunchKernelGGL(oproj_ln_kernel, dim3(B * S / 32), dim3(1024), 0, stream,
                           accPb, lP, WoB, bo, gamma, beta, q, out);
    }
}